// Round 1
// baseline (428.287 us; speedup 1.0000x reference)
//
#include <hip/hip_runtime.h>
#include <hip/hip_bf16.h>

#define N_TOK 4096
#define D_DIM 512
#define E_NUM 8
#define H_DIM 2048

typedef __attribute__((ext_vector_type(8))) short short8;
typedef __attribute__((ext_vector_type(4))) float f32x4;

__device__ inline short f2bs(float f) {
  __hip_bfloat16 h = __float2bfloat16(f);
  return *reinterpret_cast<short*>(&h);
}

// ---------- fp32 -> bf16 straight conversion (x) ----------
__global__ void cvt_kernel(const float* __restrict__ src, short* __restrict__ dst, int n4) {
  int i = blockIdx.x * blockDim.x + threadIdx.x;
  if (i < n4) {
    float4 v = reinterpret_cast<const float4*>(src)[i];
    short4 o;
    o.x = f2bs(v.x); o.y = f2bs(v.y); o.z = f2bs(v.z); o.w = f2bs(v.w);
    reinterpret_cast<short4*>(dst)[i] = o;
  }
}

// ---------- fp32 [R][C] -> bf16 [C][R] transpose-convert ----------
__global__ void tcvt_kernel(const float* __restrict__ in, short* __restrict__ out, int R, int C) {
  __shared__ float t[32][33];
  int c0 = blockIdx.x * 32, r0 = blockIdx.y * 32;
  int tx = threadIdx.x, ty = threadIdx.y;  // block (32,8)
#pragma unroll
  for (int i = 0; i < 4; ++i)
    t[ty + 8 * i][tx] = in[(size_t)(r0 + ty + 8 * i) * C + c0 + tx];
  __syncthreads();
#pragma unroll
  for (int i = 0; i < 4; ++i)
    out[(size_t)(c0 + ty + 8 * i) * R + r0 + tx] = f2bs(t[tx][ty + 8 * i]);
}

// ---------- router: logits -> softmax -> top2 -> expert lists ----------
__global__ void __launch_bounds__(64) router_kernel(
    const float* __restrict__ x, const float* __restrict__ wr,
    float* __restrict__ probs_full, int* __restrict__ e_cnt,
    int* __restrict__ e_tok, float* __restrict__ e_p) {
  int t = blockIdx.x;
  int lane = threadIdx.x;
  const float* xr = x + (size_t)t * D_DIM + lane * 8;
  float4 xa = *(const float4*)(xr);
  float4 xb = *(const float4*)(xr + 4);
  float xv[8] = {xa.x, xa.y, xa.z, xa.w, xb.x, xb.y, xb.z, xb.w};
  float acc[8] = {0, 0, 0, 0, 0, 0, 0, 0};
  const float* wrp = wr + (size_t)lane * 8 * E_NUM;
#pragma unroll
  for (int j = 0; j < 8; ++j) {
    float4 w0 = *(const float4*)(wrp + j * 8);
    float4 w1 = *(const float4*)(wrp + j * 8 + 4);
    acc[0] += xv[j] * w0.x; acc[1] += xv[j] * w0.y;
    acc[2] += xv[j] * w0.z; acc[3] += xv[j] * w0.w;
    acc[4] += xv[j] * w1.x; acc[5] += xv[j] * w1.y;
    acc[6] += xv[j] * w1.z; acc[7] += xv[j] * w1.w;
  }
#pragma unroll
  for (int e = 0; e < 8; ++e) {
    float v = acc[e];
    for (int off = 32; off; off >>= 1) v += __shfl_down(v, off);
    acc[e] = v;
  }
  if (lane == 0) {
    float m = acc[0];
    for (int e = 1; e < 8; ++e) m = fmaxf(m, acc[e]);
    float p[8], s = 0.f;
    for (int e = 0; e < 8; ++e) { p[e] = expf(acc[e] - m); s += p[e]; }
    float inv = 1.f / s;
    for (int e = 0; e < 8; ++e) { p[e] *= inv; probs_full[t * 8 + e] = p[e]; }
    int i0 = 0;
    for (int e = 1; e < 8; ++e) if (p[e] > p[i0]) i0 = e;
    int i1 = (i0 == 0) ? 1 : 0;
    for (int e = 0; e < 8; ++e) if (e != i0 && p[e] > p[i1]) i1 = e;
    float ps = p[i0] + p[i1] + 1e-10f;
    float q0 = p[i0] / ps, q1 = p[i1] / ps;
    int s0 = atomicAdd(&e_cnt[i0], 1);
    e_tok[i0 * N_TOK + s0] = t; e_p[i0 * N_TOK + s0] = q0;
    int s1 = atomicAdd(&e_cnt[i1], 1);
    e_tok[i1 * N_TOK + s1] = t; e_p[i1 * N_TOK + s1] = q1;
  }
}

// ---------- load-balance loss ----------
__global__ void __launch_bounds__(256) loss_kernel(const float* __restrict__ probs,
                                                   float* __restrict__ out_loss) {
  __shared__ float sums[8];
  if (threadIdx.x < 8) sums[threadIdx.x] = 0.f;
  __syncthreads();
  float loc[8] = {0, 0, 0, 0, 0, 0, 0, 0};
  for (int t = threadIdx.x; t < N_TOK; t += 256)
#pragma unroll
    for (int e = 0; e < 8; ++e) loc[e] += probs[t * 8 + e];
#pragma unroll
  for (int e = 0; e < 8; ++e) {
    float v = loc[e];
    for (int off = 32; off; off >>= 1) v += __shfl_down(v, off);
    if ((threadIdx.x & 63) == 0) atomicAdd(&sums[e], v);
  }
  __syncthreads();
  if (threadIdx.x == 0) {
    float lb = 0.f;
    for (int e = 0; e < 8; ++e) {
      float pe = sums[e] / (float)N_TOK;
      lb += pe * logf(pe * 8.f + 1e-10f);
    }
    out_loss[0] = 8.f * lb;
  }
}

// ---------- grouped gate/up GEMM + fused silu·up·p epilogue ----------
__global__ void __launch_bounds__(256) moe_gateup_kernel(
    const short* __restrict__ xb, const short* __restrict__ wg,
    const short* __restrict__ wu, const int* __restrict__ e_cnt,
    const int* __restrict__ e_tok, const float* __restrict__ e_p,
    float* __restrict__ combined) {
  int e = blockIdx.z;
  int n_e = e_cnt[e];
  int rt = blockIdx.y;
  if (rt * 64 >= n_e) return;
  int n0 = blockIdx.x * 64;

  __shared__ __align__(16) short As[8][64][8];   // [k-chunk][m][8]
  __shared__ __align__(16) short Bgs[8][64][8];  // [k-chunk][n][8]
  __shared__ __align__(16) short Bus[8][64][8];
  __shared__ int s_tok[64];
  __shared__ float s_pr[64];

  int tid = threadIdx.x;
  if (tid < 64) {
    int r = rt * 64 + tid;
    bool v = r < n_e;
    s_tok[tid] = v ? e_tok[e * N_TOK + r] : -1;
    s_pr[tid] = v ? e_p[e * N_TOK + r] : 0.f;
  }
  __syncthreads();

  int lane = tid & 63, wid = tid >> 6;
  int ml = lane & 15, quad = lane >> 4;
  int m0 = wid * 16;
  f32x4 accG[4] = {{0, 0, 0, 0}, {0, 0, 0, 0}, {0, 0, 0, 0}, {0, 0, 0, 0}};
  f32x4 accU[4] = {{0, 0, 0, 0}, {0, 0, 0, 0}, {0, 0, 0, 0}, {0, 0, 0, 0}};
  const short* wgBase = wg + ((size_t)e * H_DIM + n0) * D_DIM;
  const short* wuBase = wu + ((size_t)e * H_DIM + n0) * D_DIM;

  for (int kt = 0; kt < D_DIM / 64; ++kt) {
    int kb = kt * 64;
#pragma unroll
    for (int it = 0; it < 2; ++it) {
      int q = tid + it * 256;
      int m = q >> 3, c = q & 7;
      int tok = s_tok[m];
      short8 av = {0, 0, 0, 0, 0, 0, 0, 0};
      if (tok >= 0) av = *(const short8*)(xb + (size_t)tok * D_DIM + kb + c * 8);
      *(short8*)&As[c][m][0] = av;
      *(short8*)&Bgs[c][m][0] = *(const short8*)(wgBase + (size_t)m * D_DIM + kb + c * 8);
      *(short8*)&Bus[c][m][0] = *(const short8*)(wuBase + (size_t)m * D_DIM + kb + c * 8);
    }
    __syncthreads();
#pragma unroll
    for (int ks = 0; ks < 2; ++ks) {
      short8 a = *(const short8*)&As[ks * 4 + quad][m0 + ml][0];
#pragma unroll
      for (int nf = 0; nf < 4; ++nf) {
        short8 bg = *(const short8*)&Bgs[ks * 4 + quad][nf * 16 + ml][0];
        short8 bu = *(const short8*)&Bus[ks * 4 + quad][nf * 16 + ml][0];
        accG[nf] = __builtin_amdgcn_mfma_f32_16x16x32_bf16(a, bg, accG[nf], 0, 0, 0);
        accU[nf] = __builtin_amdgcn_mfma_f32_16x16x32_bf16(a, bu, accU[nf], 0, 0, 0);
      }
    }
    __syncthreads();
  }

#pragma unroll
  for (int nf = 0; nf < 4; ++nf) {
#pragma unroll
    for (int r = 0; r < 4; ++r) {
      int rl = m0 + quad * 4 + r;
      int tok = s_tok[rl];
      if (tok >= 0) {
        float g = accG[nf][r], u = accU[nf][r];
        float val = s_pr[rl] * (g / (1.f + __expf(-g))) * u;
        atomicAdd(&combined[(size_t)tok * H_DIM + n0 + nf * 16 + ml], val);
      }
    }
  }
}

// ---------- down GEMM: combined[4096,2048] @ w_down -> out ----------
__global__ void __launch_bounds__(256) down_kernel(
    const float* __restrict__ combined, const short* __restrict__ wd,
    float* __restrict__ out) {
  int d0 = blockIdx.x * 64;
  int t0 = blockIdx.y * 64;
  __shared__ __align__(16) short As[8][64][8];
  __shared__ __align__(16) short Bs[8][64][8];
  int tid = threadIdx.x;
  int lane = tid & 63, wid = tid >> 6;
  int ml = lane & 15, quad = lane >> 4;
  int m0 = wid * 16;
  f32x4 acc[4] = {{0, 0, 0, 0}, {0, 0, 0, 0}, {0, 0, 0, 0}, {0, 0, 0, 0}};

  for (int kt = 0; kt < H_DIM / 64; ++kt) {
    int kb = kt * 64;
#pragma unroll
    for (int it = 0; it < 2; ++it) {
      int q = tid + it * 256;
      int m = q >> 3, c = q & 7;
      const float4* src = (const float4*)(combined + (size_t)(t0 + m) * H_DIM + kb + c * 8);
      float4 v0 = src[0], v1 = src[1];
      short8 s;
      s[0] = f2bs(v0.x); s[1] = f2bs(v0.y); s[2] = f2bs(v0.z); s[3] = f2bs(v0.w);
      s[4] = f2bs(v1.x); s[5] = f2bs(v1.y); s[6] = f2bs(v1.z); s[7] = f2bs(v1.w);
      *(short8*)&As[c][m][0] = s;
      *(short8*)&Bs[c][m][0] = *(const short8*)(wd + (size_t)(d0 + m) * H_DIM + kb + c * 8);
    }
    __syncthreads();
#pragma unroll
    for (int ks = 0; ks < 2; ++ks) {
      short8 a = *(const short8*)&As[ks * 4 + quad][m0 + ml][0];
#pragma unroll
      for (int nf = 0; nf < 4; ++nf) {
        short8 b = *(const short8*)&Bs[ks * 4 + quad][nf * 16 + ml][0];
        acc[nf] = __builtin_amdgcn_mfma_f32_16x16x32_bf16(a, b, acc[nf], 0, 0, 0);
      }
    }
    __syncthreads();
  }

#pragma unroll
  for (int nf = 0; nf < 4; ++nf)
#pragma unroll
    for (int r = 0; r < 4; ++r) {
      int t = t0 + m0 + quad * 4 + r;
      out[(size_t)t * D_DIM + d0 + nf * 16 + ml] = acc[nf][r];
    }
}

extern "C" void kernel_launch(void* const* d_in, const int* in_sizes, int n_in,
                              void* d_out, int out_size, void* d_ws, size_t ws_size,
                              hipStream_t stream) {
  const float* x = (const float*)d_in[0];
  const float* wr = (const float*)d_in[1];
  const float* wg = (const float*)d_in[2];
  const float* wu = (const float*)d_in[3];
  const float* wd = (const float*)d_in[4];
  float* out = (float*)d_out;

  char* ws = (char*)d_ws;
  size_t off = 0;
  auto alloc = [&](size_t bytes) {
    char* p = ws + off;
    off += (bytes + 255) & ~(size_t)255;
    return p;
  };
  short* xb = (short*)alloc((size_t)N_TOK * D_DIM * 2);
  short* wgb = (short*)alloc((size_t)E_NUM * H_DIM * D_DIM * 2);  // [e*H+h][d]
  short* wub = (short*)alloc((size_t)E_NUM * H_DIM * D_DIM * 2);
  short* wdb = (short*)alloc((size_t)D_DIM * H_DIM * 2);          // [d][h]
  float* combined = (float*)alloc((size_t)N_TOK * H_DIM * 4);
  float* probs = (float*)alloc((size_t)N_TOK * E_NUM * 4);
  int* e_cnt = (int*)alloc(256);
  int* e_tok = (int*)alloc((size_t)E_NUM * N_TOK * 4);
  float* e_p = (float*)alloc((size_t)E_NUM * N_TOK * 4);

  hipMemsetAsync(e_cnt, 0, 32, stream);
  hipMemsetAsync(combined, 0, (size_t)N_TOK * H_DIM * 4, stream);

  cvt_kernel<<<N_TOK * D_DIM / 4 / 256, 256, 0, stream>>>(x, xb, N_TOK * D_DIM / 4);
  tcvt_kernel<<<dim3(E_NUM * H_DIM / 32, D_DIM / 32), dim3(32, 8), 0, stream>>>(
      wg, wgb, D_DIM, E_NUM * H_DIM);
  tcvt_kernel<<<dim3(E_NUM * H_DIM / 32, D_DIM / 32), dim3(32, 8), 0, stream>>>(
      wu, wub, D_DIM, E_NUM * H_DIM);
  tcvt_kernel<<<dim3(D_DIM / 32, H_DIM / 32), dim3(32, 8), 0, stream>>>(
      wd, wdb, H_DIM, D_DIM);
  router_kernel<<<N_TOK, 64, 0, stream>>>(x, wr, probs, e_cnt, e_tok, e_p);
  loss_kernel<<<1, 256, 0, stream>>>(probs, out + (size_t)N_TOK * D_DIM);
  moe_gateup_kernel<<<dim3(H_DIM / 64, N_TOK / 64, E_NUM), 256, 0, stream>>>(
      xb, wgb, wub, e_cnt, e_tok, e_p, combined);
  down_kernel<<<dim3(D_DIM / 64, N_TOK / 64), 256, 0, stream>>>(combined, wdb, out);
}

// Round 2
// 348.830 us; speedup vs baseline: 1.2278x; 1.2278x over previous
//
#include <hip/hip_runtime.h>
#include <hip/hip_bf16.h>

#define N_TOK 4096
#define D_DIM 512
#define E_NUM 8
#define H_DIM 2048

typedef __attribute__((ext_vector_type(8))) short short8;
typedef __attribute__((ext_vector_type(4))) float f32x4;

__device__ inline short f2bs(float f) {
  __hip_bfloat16 h = __float2bfloat16(f);
  return *reinterpret_cast<short*>(&h);
}

// async global->LDS, 16 B per lane; lds dest is wave-uniform base + lane*16
__device__ inline void llds16(const short* g, short* l) {
  __builtin_amdgcn_global_load_lds(
      (const __attribute__((address_space(1))) void*)g,
      (__attribute__((address_space(3))) void*)l, 16, 0, 0);
}

// ---------- fp32 -> bf16 straight conversion (x) ----------
__global__ void cvt_kernel(const float* __restrict__ src, short* __restrict__ dst, int n4) {
  int i = blockIdx.x * blockDim.x + threadIdx.x;
  if (i < n4) {
    float4 v = reinterpret_cast<const float4*>(src)[i];
    short4 o;
    o.x = f2bs(v.x); o.y = f2bs(v.y); o.z = f2bs(v.z); o.w = f2bs(v.w);
    reinterpret_cast<short4*>(dst)[i] = o;
  }
}

// ---------- fp32 [R][C] -> bf16 [C][R] transpose-convert ----------
__global__ void tcvt_kernel(const float* __restrict__ in, short* __restrict__ out, int R, int C) {
  __shared__ float t[32][33];
  int c0 = blockIdx.x * 32, r0 = blockIdx.y * 32;
  int tx = threadIdx.x, ty = threadIdx.y;  // block (32,8)
#pragma unroll
  for (int i = 0; i < 4; ++i)
    t[ty + 8 * i][tx] = in[(size_t)(r0 + ty + 8 * i) * C + c0 + tx];
  __syncthreads();
#pragma unroll
  for (int i = 0; i < 4; ++i)
    out[(size_t)(c0 + ty + 8 * i) * R + r0 + tx] = f2bs(t[tx][ty + 8 * i]);
}

// ---------- router: logits -> softmax -> top2 -> expert lists ----------
// e_tok entry encodes token*2 + slot (slot 0 = top-1, slot 1 = top-2)
__global__ void __launch_bounds__(64) router_kernel(
    const float* __restrict__ x, const float* __restrict__ wr,
    float* __restrict__ probs_full, int* __restrict__ e_cnt,
    int* __restrict__ e_tok, float* __restrict__ e_p) {
  int t = blockIdx.x;
  int lane = threadIdx.x;
  const float* xr = x + (size_t)t * D_DIM + lane * 8;
  float4 xa = *(const float4*)(xr);
  float4 xb = *(const float4*)(xr + 4);
  float xv[8] = {xa.x, xa.y, xa.z, xa.w, xb.x, xb.y, xb.z, xb.w};
  float acc[8] = {0, 0, 0, 0, 0, 0, 0, 0};
  const float* wrp = wr + (size_t)lane * 8 * E_NUM;
#pragma unroll
  for (int j = 0; j < 8; ++j) {
    float4 w0 = *(const float4*)(wrp + j * 8);
    float4 w1 = *(const float4*)(wrp + j * 8 + 4);
    acc[0] += xv[j] * w0.x; acc[1] += xv[j] * w0.y;
    acc[2] += xv[j] * w0.z; acc[3] += xv[j] * w0.w;
    acc[4] += xv[j] * w1.x; acc[5] += xv[j] * w1.y;
    acc[6] += xv[j] * w1.z; acc[7] += xv[j] * w1.w;
  }
#pragma unroll
  for (int e = 0; e < 8; ++e) {
    float v = acc[e];
    for (int off = 32; off; off >>= 1) v += __shfl_down(v, off);
    acc[e] = v;
  }
  if (lane == 0) {
    float m = acc[0];
    for (int e = 1; e < 8; ++e) m = fmaxf(m, acc[e]);
    float p[8], s = 0.f;
    for (int e = 0; e < 8; ++e) { p[e] = expf(acc[e] - m); s += p[e]; }
    float inv = 1.f / s;
    for (int e = 0; e < 8; ++e) { p[e] *= inv; probs_full[t * 8 + e] = p[e]; }
    int i0 = 0;
    for (int e = 1; e < 8; ++e) if (p[e] > p[i0]) i0 = e;
    int i1 = (i0 == 0) ? 1 : 0;
    for (int e = 0; e < 8; ++e) if (e != i0 && p[e] > p[i1]) i1 = e;
    float ps = p[i0] + p[i1] + 1e-10f;
    float q0 = p[i0] / ps, q1 = p[i1] / ps;
    int s0 = atomicAdd(&e_cnt[i0], 1);
    e_tok[i0 * N_TOK + s0] = t * 2 + 0; e_p[i0 * N_TOK + s0] = q0;
    int s1 = atomicAdd(&e_cnt[i1], 1);
    e_tok[i1 * N_TOK + s1] = t * 2 + 1; e_p[i1 * N_TOK + s1] = q1;
  }
}

// ---------- load-balance loss ----------
__global__ void __launch_bounds__(256) loss_kernel(const float* __restrict__ probs,
                                                   float* __restrict__ out_loss) {
  __shared__ float sums[8];
  if (threadIdx.x < 8) sums[threadIdx.x] = 0.f;
  __syncthreads();
  float loc[8] = {0, 0, 0, 0, 0, 0, 0, 0};
  for (int t = threadIdx.x; t < N_TOK; t += 256)
#pragma unroll
    for (int e = 0; e < 8; ++e) loc[e] += probs[t * 8 + e];
#pragma unroll
  for (int e = 0; e < 8; ++e) {
    float v = loc[e];
    for (int off = 32; off; off >>= 1) v += __shfl_down(v, off);
    if ((threadIdx.x & 63) == 0) atomicAdd(&sums[e], v);
  }
  __syncthreads();
  if (threadIdx.x == 0) {
    float lb = 0.f;
    for (int e = 0; e < 8; ++e) {
      float pe = sums[e] / (float)N_TOK;
      lb += pe * logf(pe * 8.f + 1e-10f);
    }
    out_loss[0] = 8.f * lb;
  }
}

// ---------- grouped gate/up GEMM (128x64 tile, global_load_lds, XOR swizzle) ----------
// writes bf16 act[(2t+slot)][H] = p * silu(g) * u  (non-atomic, each row once)
__global__ void __launch_bounds__(256) moe_gateup_kernel(
    const short* __restrict__ xb, const short* __restrict__ wg,
    const short* __restrict__ wu, const int* __restrict__ e_cnt,
    const int* __restrict__ e_tok, const float* __restrict__ e_p,
    short* __restrict__ act) {
  __shared__ __align__(16) short As[128 * 64];   // [m][chunk^(m&7)]
  __shared__ __align__(16) short Bgs[64 * 64];
  __shared__ __align__(16) short Bus[64 * 64];
  __shared__ int s_row[128];
  __shared__ float s_pr[128];

  int e = blockIdx.z;
  int n_e = e_cnt[e];
  int rt = blockIdx.y;
  if (rt * 128 >= n_e) return;
  int h0 = blockIdx.x * 64;
  int tid = threadIdx.x;
  int lane = tid & 63, wid = tid >> 6;

  if (tid < 128) {
    int r = rt * 128 + tid;
    bool v = r < n_e;
    s_row[tid] = v ? e_tok[e * N_TOK + r] : -1;
    s_pr[tid] = v ? e_p[e * N_TOK + r] : 0.f;
  }
  __syncthreads();

  // per-lane global bases (fixed across K loop)
  int cg = (lane & 7) ^ (lane >> 3);  // swizzled global chunk for this lane
  const short* baseA[8];
  const short* baseB[8];
  if (wid < 2) {
#pragma unroll
    for (int jj = 0; jj < 8; ++jj) {
      int r = 8 * (wid * 8 + jj) + (lane >> 3);
      int row = s_row[r];
      int t = (row < 0) ? 0 : (row >> 1);
      baseA[jj] = xb + (size_t)t * D_DIM + cg * 8;
    }
  } else {
    const short* wB = ((wid == 2) ? wg : wu) + (size_t)e * H_DIM * D_DIM;
#pragma unroll
    for (int jj = 0; jj < 8; ++jj) {
      int h = h0 + 8 * jj + (lane >> 3);
      baseB[jj] = wB + (size_t)h * D_DIM + cg * 8;
    }
  }

  int ml = lane & 15, quad = lane >> 4;
  int m0w = (wid & 1) * 64, n0w = (wid >> 1) * 32;
  f32x4 accG[4][2], accU[4][2];
#pragma unroll
  for (int mf = 0; mf < 4; ++mf)
#pragma unroll
    for (int nf = 0; nf < 2; ++nf) {
      accG[mf][nf] = (f32x4){0, 0, 0, 0};
      accU[mf][nf] = (f32x4){0, 0, 0, 0};
    }
  short* dstB = (wid == 2) ? Bgs : Bus;

  for (int kt = 0; kt < D_DIM / 64; ++kt) {
    int kb = kt * 64;
    if (wid < 2) {
#pragma unroll
      for (int jj = 0; jj < 8; ++jj)
        llds16(baseA[jj] + kb, As + (wid * 8 + jj) * 512);
    } else {
#pragma unroll
      for (int jj = 0; jj < 8; ++jj)
        llds16(baseB[jj] + kb, dstB + jj * 512);
    }
    __syncthreads();
#pragma unroll
    for (int ks = 0; ks < 2; ++ks) {
      short8 a[4], bg[2], bu[2];
#pragma unroll
      for (int mf = 0; mf < 4; ++mf) {
        int m = m0w + mf * 16 + ml;
        a[mf] = *(const short8*)&As[m * 64 + (((quad + ks * 4) ^ (ml & 7)) * 8)];
      }
#pragma unroll
      for (int nf = 0; nf < 2; ++nf) {
        int n = n0w + nf * 16 + ml;
        int cs = ((quad + ks * 4) ^ (ml & 7)) * 8;
        bg[nf] = *(const short8*)&Bgs[n * 64 + cs];
        bu[nf] = *(const short8*)&Bus[n * 64 + cs];
      }
#pragma unroll
      for (int mf = 0; mf < 4; ++mf)
#pragma unroll
        for (int nf = 0; nf < 2; ++nf) {
          accG[mf][nf] = __builtin_amdgcn_mfma_f32_16x16x32_bf16(a[mf], bg[nf], accG[mf][nf], 0, 0, 0);
          accU[mf][nf] = __builtin_amdgcn_mfma_f32_16x16x32_bf16(a[mf], bu[nf], accU[mf][nf], 0, 0, 0);
        }
    }
    __syncthreads();
  }

#pragma unroll
  for (int mf = 0; mf < 4; ++mf)
#pragma unroll
    for (int r = 0; r < 4; ++r) {
      int rl = m0w + mf * 16 + quad * 4 + r;
      int arow = s_row[rl];
      if (arow >= 0) {
        float pr = s_pr[rl];
#pragma unroll
        for (int nf = 0; nf < 2; ++nf) {
          float g = accG[mf][nf][r], u = accU[mf][nf][r];
          float val = pr * (g / (1.f + __expf(-g))) * u;
          act[(size_t)arow * H_DIM + h0 + n0w + nf * 16 + ml] = f2bs(val);
        }
      }
    }
}

// ---------- down GEMM: out[t] = (act[2t] + act[2t+1]) @ wd, as K=4096 view ----------
// Ksplit=2 across blockIdx.z; fp32 atomicAdd into zeroed out
__global__ void __launch_bounds__(256) down_kernel(
    const short* __restrict__ act, const short* __restrict__ wd,
    float* __restrict__ out) {
  __shared__ __align__(16) short As[128 * 64];
  __shared__ __align__(16) short Bs[64 * 64];
  int d0 = blockIdx.x * 64;
  int t0 = blockIdx.y * 128;
  int ksb = blockIdx.z;  // kt range [ksb*32, ksb*32+32)
  int tid = threadIdx.x, lane = tid & 63, wid = tid >> 6;
  int cg = (lane & 7) ^ (lane >> 3);

  const short* baseA[8];
  const short* baseB[4];
  if (wid < 2) {
#pragma unroll
    for (int jj = 0; jj < 8; ++jj) {
      int r = 8 * (wid * 8 + jj) + (lane >> 3);
      baseA[jj] = act + (size_t)(2 * (t0 + r)) * H_DIM + cg * 8;
    }
  } else {
#pragma unroll
    for (int jj = 0; jj < 4; ++jj) {
      int d = d0 + 8 * ((wid - 2) * 4 + jj) + (lane >> 3);
      baseB[jj] = wd + (size_t)d * H_DIM + cg * 8;
    }
  }

  int ml = lane & 15, quad = lane >> 4;
  int m0w = (wid & 1) * 64, n0w = (wid >> 1) * 32;
  f32x4 acc[4][2];
#pragma unroll
  for (int mf = 0; mf < 4; ++mf)
#pragma unroll
    for (int nf = 0; nf < 2; ++nf) acc[mf][nf] = (f32x4){0, 0, 0, 0};

  for (int kt = ksb * 32; kt < ksb * 32 + 32; ++kt) {
    int slot = kt & 1;
    int kh = (kt >> 1) * 64;
    if (wid < 2) {
#pragma unroll
      for (int jj = 0; jj < 8; ++jj)
        llds16(baseA[jj] + (size_t)slot * H_DIM + kh, As + (wid * 8 + jj) * 512);
    } else {
#pragma unroll
      for (int jj = 0; jj < 4; ++jj)
        llds16(baseB[jj] + kh, Bs + ((wid - 2) * 4 + jj) * 512);
    }
    __syncthreads();
#pragma unroll
    for (int ks = 0; ks < 2; ++ks) {
      short8 a[4], b[2];
#pragma unroll
      for (int mf = 0; mf < 4; ++mf) {
        int m = m0w + mf * 16 + ml;
        a[mf] = *(const short8*)&As[m * 64 + (((quad + ks * 4) ^ (ml & 7)) * 8)];
      }
#pragma unroll
      for (int nf = 0; nf < 2; ++nf) {
        int n = n0w + nf * 16 + ml;
        b[nf] = *(const short8*)&Bs[n * 64 + (((quad + ks * 4) ^ (ml & 7)) * 8)];
      }
#pragma unroll
      for (int mf = 0; mf < 4; ++mf)
#pragma unroll
        for (int nf = 0; nf < 2; ++nf)
          acc[mf][nf] = __builtin_amdgcn_mfma_f32_16x16x32_bf16(a[mf], b[nf], acc[mf][nf], 0, 0, 0);
    }
    __syncthreads();
  }

#pragma unroll
  for (int mf = 0; mf < 4; ++mf)
#pragma unroll
    for (int r = 0; r < 4; ++r) {
      int t = t0 + m0w + mf * 16 + quad * 4 + r;
#pragma unroll
      for (int nf = 0; nf < 2; ++nf)
        atomicAdd(&out[(size_t)t * D_DIM + d0 + n0w + nf * 16 + ml], acc[mf][nf][r]);
    }
}

extern "C" void kernel_launch(void* const* d_in, const int* in_sizes, int n_in,
                              void* d_out, int out_size, void* d_ws, size_t ws_size,
                              hipStream_t stream) {
  const float* x = (const float*)d_in[0];
  const float* wr = (const float*)d_in[1];
  const float* wg = (const float*)d_in[2];
  const float* wu = (const float*)d_in[3];
  const float* wd = (const float*)d_in[4];
  float* out = (float*)d_out;

  char* ws = (char*)d_ws;
  size_t off = 0;
  auto alloc = [&](size_t bytes) {
    char* p = ws + off;
    off += (bytes + 255) & ~(size_t)255;
    return p;
  };
  short* xb = (short*)alloc((size_t)N_TOK * D_DIM * 2);
  short* wgb = (short*)alloc((size_t)E_NUM * H_DIM * D_DIM * 2);  // [e*H+h][d]
  short* wub = (short*)alloc((size_t)E_NUM * H_DIM * D_DIM * 2);
  short* wdb = (short*)alloc((size_t)D_DIM * H_DIM * 2);          // [d][h]
  short* act = (short*)alloc((size_t)N_TOK * 2 * H_DIM * 2);      // [2t+slot][H]
  float* probs = (float*)alloc((size_t)N_TOK * E_NUM * 4);
  int* e_cnt = (int*)alloc(256);
  int* e_tok = (int*)alloc((size_t)E_NUM * N_TOK * 4);
  float* e_p = (float*)alloc((size_t)E_NUM * N_TOK * 4);

  hipMemsetAsync(e_cnt, 0, 32, stream);
  hipMemsetAsync(out, 0, (size_t)out_size * 4, stream);

  cvt_kernel<<<N_TOK * D_DIM / 4 / 256, 256, 0, stream>>>(x, xb, N_TOK * D_DIM / 4);
  tcvt_kernel<<<dim3(E_NUM * H_DIM / 32, D_DIM / 32), dim3(32, 8), 0, stream>>>(
      wg, wgb, D_DIM, E_NUM * H_DIM);
  tcvt_kernel<<<dim3(E_NUM * H_DIM / 32, D_DIM / 32), dim3(32, 8), 0, stream>>>(
      wu, wub, D_DIM, E_NUM * H_DIM);
  tcvt_kernel<<<dim3(D_DIM / 32, H_DIM / 32), dim3(32, 8), 0, stream>>>(
      wd, wdb, H_DIM, D_DIM);
  router_kernel<<<N_TOK, 64, 0, stream>>>(x, wr, probs, e_cnt, e_tok, e_p);
  loss_kernel<<<1, 256, 0, stream>>>(probs, out + (size_t)N_TOK * D_DIM);
  moe_gateup_kernel<<<dim3(H_DIM / 64, N_TOK / 128, E_NUM), 256, 0, stream>>>(
      xb, wgb, wub, e_cnt, e_tok, e_p, act);
  down_kernel<<<dim3(D_DIM / 64, N_TOK / 128, 2), 256, 0, stream>>>(act, wdb, out);
}

// Round 3
// 301.056 us; speedup vs baseline: 1.4226x; 1.1587x over previous
//
#include <hip/hip_runtime.h>
#include <hip/hip_bf16.h>

#define N_TOK 4096
#define D_DIM 512
#define E_NUM 8
#define H_DIM 2048

typedef __attribute__((ext_vector_type(8))) short short8;
typedef __attribute__((ext_vector_type(4))) float f32x4;

__device__ inline short f2bs(float f) {
  __hip_bfloat16 h = __float2bfloat16(f);
  return *reinterpret_cast<short*>(&h);
}

// async global->LDS, 16 B per lane; lds dest is wave-uniform base + lane*16
__device__ inline void llds16(const short* g, short* l) {
  __builtin_amdgcn_global_load_lds(
      (const __attribute__((address_space(1))) void*)g,
      (__attribute__((address_space(3))) void*)l, 16, 0, 0);
}

// ---------- fp32 -> bf16 straight conversion (x) ----------
__global__ void cvt_kernel(const float* __restrict__ src, short* __restrict__ dst, int n4) {
  int i = blockIdx.x * blockDim.x + threadIdx.x;
  if (i < n4) {
    float4 v = reinterpret_cast<const float4*>(src)[i];
    short4 o;
    o.x = f2bs(v.x); o.y = f2bs(v.y); o.z = f2bs(v.z); o.w = f2bs(v.w);
    reinterpret_cast<short4*>(dst)[i] = o;
  }
}

// ---------- fp32 [R][C] -> bf16 [C][R] transpose-convert ----------
__global__ void tcvt_kernel(const float* __restrict__ in, short* __restrict__ out, int R, int C) {
  __shared__ float t[32][33];
  int c0 = blockIdx.x * 32, r0 = blockIdx.y * 32;
  int tx = threadIdx.x, ty = threadIdx.y;  // block (32,8)
#pragma unroll
  for (int i = 0; i < 4; ++i)
    t[ty + 8 * i][tx] = in[(size_t)(r0 + ty + 8 * i) * C + c0 + tx];
  __syncthreads();
#pragma unroll
  for (int i = 0; i < 4; ++i)
    out[(size_t)(c0 + ty + 8 * i) * R + r0 + tx] = f2bs(t[tx][ty + 8 * i]);
}

// ---------- router: one token per thread, block-aggregated expert atomics ----------
// e_tok entry encodes token*2 + slot (slot 0 = top-1, slot 1 = top-2)
__global__ void __launch_bounds__(64) router_kernel(
    const float* __restrict__ x, const float* __restrict__ wr,
    float* __restrict__ probs_full, int* __restrict__ e_cnt,
    int* __restrict__ e_tok, float* __restrict__ e_p) {
  __shared__ int h_cnt[E_NUM];
  __shared__ int h_base[E_NUM];
  int tid = threadIdx.x;
  int t = blockIdx.x * 64 + tid;
  if (tid < E_NUM) h_cnt[tid] = 0;
  __syncthreads();

  const float* xr = x + (size_t)t * D_DIM;
  float acc[8] = {0, 0, 0, 0, 0, 0, 0, 0};
#pragma unroll 4
  for (int j = 0; j < D_DIM; j += 4) {
    float4 xv = *(const float4*)(xr + j);
    // wr indexed uniformly across the wave -> scalar loads
    const float* w0 = wr + (size_t)j * E_NUM;
#pragma unroll
    for (int e = 0; e < 8; ++e) {
      acc[e] += xv.x * w0[e] + xv.y * w0[8 + e] + xv.z * w0[16 + e] + xv.w * w0[24 + e];
    }
  }
  float m = acc[0];
#pragma unroll
  for (int e = 1; e < 8; ++e) m = fmaxf(m, acc[e]);
  float p[8], s = 0.f;
#pragma unroll
  for (int e = 0; e < 8; ++e) { p[e] = expf(acc[e] - m); s += p[e]; }
  float inv = 1.f / s;
#pragma unroll
  for (int e = 0; e < 8; ++e) p[e] *= inv;
  float4 pv0 = {p[0], p[1], p[2], p[3]}, pv1 = {p[4], p[5], p[6], p[7]};
  *(float4*)(probs_full + t * 8) = pv0;
  *(float4*)(probs_full + t * 8 + 4) = pv1;

  int i0 = 0;
#pragma unroll
  for (int e = 1; e < 8; ++e) if (p[e] > p[i0]) i0 = e;
  int i1 = (i0 == 0) ? 1 : 0;
#pragma unroll
  for (int e = 0; e < 8; ++e) if (e != i0 && p[e] > p[i1]) i1 = e;
  float ps = p[i0] + p[i1] + 1e-10f;
  float q0 = p[i0] / ps, q1 = p[i1] / ps;

  // local slots via LDS atomics, one global atomic per expert per block
  int l0 = atomicAdd(&h_cnt[i0], 1);
  int l1 = atomicAdd(&h_cnt[i1], 1);
  __syncthreads();
  if (tid < E_NUM) h_base[tid] = h_cnt[tid] ? atomicAdd(&e_cnt[tid], h_cnt[tid]) : 0;
  __syncthreads();
  int s0 = h_base[i0] + l0;
  e_tok[i0 * N_TOK + s0] = t * 2 + 0; e_p[i0 * N_TOK + s0] = q0;
  int s1 = h_base[i1] + l1;
  e_tok[i1 * N_TOK + s1] = t * 2 + 1; e_p[i1 * N_TOK + s1] = q1;
}

// ---------- load-balance loss ----------
__global__ void __launch_bounds__(256) loss_kernel(const float* __restrict__ probs,
                                                   float* __restrict__ out_loss) {
  __shared__ float sums[8];
  if (threadIdx.x < 8) sums[threadIdx.x] = 0.f;
  __syncthreads();
  float loc[8] = {0, 0, 0, 0, 0, 0, 0, 0};
  for (int t = threadIdx.x; t < N_TOK; t += 256)
#pragma unroll
    for (int e = 0; e < 8; ++e) loc[e] += probs[t * 8 + e];
#pragma unroll
  for (int e = 0; e < 8; ++e) {
    float v = loc[e];
    for (int off = 32; off; off >>= 1) v += __shfl_down(v, off);
    if ((threadIdx.x & 63) == 0) atomicAdd(&sums[e], v);
  }
  __syncthreads();
  if (threadIdx.x == 0) {
    float lb = 0.f;
    for (int e = 0; e < 8; ++e) {
      float pe = sums[e] / (float)N_TOK;
      lb += pe * logf(pe * 8.f + 1e-10f);
    }
    out_loss[0] = 8.f * lb;
  }
}

// ---------- grouped gate/up GEMM (128x64 tile, global_load_lds, XOR swizzle) ----------
// writes bf16 act[(2t+slot)][H] = p * silu(g) * u  (non-atomic, each row once)
__global__ void __launch_bounds__(256) moe_gateup_kernel(
    const short* __restrict__ xb, const short* __restrict__ wg,
    const short* __restrict__ wu, const int* __restrict__ e_cnt,
    const int* __restrict__ e_tok, const float* __restrict__ e_p,
    short* __restrict__ act) {
  __shared__ __align__(16) short As[128 * 64];   // [m][chunk^(m&7)]
  __shared__ __align__(16) short Bgs[64 * 64];
  __shared__ __align__(16) short Bus[64 * 64];
  __shared__ int s_row[128];
  __shared__ float s_pr[128];

  int e = blockIdx.z;
  int n_e = e_cnt[e];
  int rt = blockIdx.y;
  if (rt * 128 >= n_e) return;
  int h0 = blockIdx.x * 64;
  int tid = threadIdx.x;
  int lane = tid & 63, wid = tid >> 6;

  if (tid < 128) {
    int r = rt * 128 + tid;
    bool v = r < n_e;
    s_row[tid] = v ? e_tok[e * N_TOK + r] : -1;
    s_pr[tid] = v ? e_p[e * N_TOK + r] : 0.f;
  }
  __syncthreads();

  // per-lane global bases (fixed across K loop)
  int cg = (lane & 7) ^ (lane >> 3);  // swizzled global chunk for this lane
  const short* baseA[8];
  const short* baseB[8];
  if (wid < 2) {
#pragma unroll
    for (int jj = 0; jj < 8; ++jj) {
      int r = 8 * (wid * 8 + jj) + (lane >> 3);
      int row = s_row[r];
      int t = (row < 0) ? 0 : (row >> 1);
      baseA[jj] = xb + (size_t)t * D_DIM + cg * 8;
    }
  } else {
    const short* wB = ((wid == 2) ? wg : wu) + (size_t)e * H_DIM * D_DIM;
#pragma unroll
    for (int jj = 0; jj < 8; ++jj) {
      int h = h0 + 8 * jj + (lane >> 3);
      baseB[jj] = wB + (size_t)h * D_DIM + cg * 8;
    }
  }

  int ml = lane & 15, quad = lane >> 4;
  int m0w = (wid & 1) * 64, n0w = (wid >> 1) * 32;
  f32x4 accG[4][2], accU[4][2];
#pragma unroll
  for (int mf = 0; mf < 4; ++mf)
#pragma unroll
    for (int nf = 0; nf < 2; ++nf) {
      accG[mf][nf] = (f32x4){0, 0, 0, 0};
      accU[mf][nf] = (f32x4){0, 0, 0, 0};
    }
  short* dstB = (wid == 2) ? Bgs : Bus;

  for (int kt = 0; kt < D_DIM / 64; ++kt) {
    int kb = kt * 64;
    if (wid < 2) {
#pragma unroll
      for (int jj = 0; jj < 8; ++jj)
        llds16(baseA[jj] + kb, As + (wid * 8 + jj) * 512);
    } else {
#pragma unroll
      for (int jj = 0; jj < 8; ++jj)
        llds16(baseB[jj] + kb, dstB + jj * 512);
    }
    __syncthreads();
#pragma unroll
    for (int ks = 0; ks < 2; ++ks) {
      short8 a[4], bg[2], bu[2];
#pragma unroll
      for (int mf = 0; mf < 4; ++mf) {
        int m = m0w + mf * 16 + ml;
        a[mf] = *(const short8*)&As[m * 64 + (((quad + ks * 4) ^ (ml & 7)) * 8)];
      }
#pragma unroll
      for (int nf = 0; nf < 2; ++nf) {
        int n = n0w + nf * 16 + ml;
        int cs = ((quad + ks * 4) ^ (ml & 7)) * 8;
        bg[nf] = *(const short8*)&Bgs[n * 64 + cs];
        bu[nf] = *(const short8*)&Bus[n * 64 + cs];
      }
#pragma unroll
      for (int mf = 0; mf < 4; ++mf)
#pragma unroll
        for (int nf = 0; nf < 2; ++nf) {
          accG[mf][nf] = __builtin_amdgcn_mfma_f32_16x16x32_bf16(a[mf], bg[nf], accG[mf][nf], 0, 0, 0);
          accU[mf][nf] = __builtin_amdgcn_mfma_f32_16x16x32_bf16(a[mf], bu[nf], accU[mf][nf], 0, 0, 0);
        }
    }
    __syncthreads();
  }

#pragma unroll
  for (int mf = 0; mf < 4; ++mf)
#pragma unroll
    for (int r = 0; r < 4; ++r) {
      int rl = m0w + mf * 16 + quad * 4 + r;
      int arow = s_row[rl];
      if (arow >= 0) {
        float pr = s_pr[rl];
#pragma unroll
        for (int nf = 0; nf < 2; ++nf) {
          float g = accG[mf][nf][r], u = accU[mf][nf][r];
          float val = pr * (g / (1.f + __expf(-g))) * u;
          act[(size_t)arow * H_DIM + h0 + n0w + nf * 16 + ml] = f2bs(val);
        }
      }
    }
}

// ---------- down GEMM: out[t] = (act[2t] + act[2t+1]) @ wd, as K=4096 view ----------
// Ksplit=2 across blockIdx.z; fp32 atomicAdd into zeroed out
__global__ void __launch_bounds__(256) down_kernel(
    const short* __restrict__ act, const short* __restrict__ wd,
    float* __restrict__ out) {
  __shared__ __align__(16) short As[128 * 64];
  __shared__ __align__(16) short Bs[64 * 64];
  int d0 = blockIdx.x * 64;
  int t0 = blockIdx.y * 128;
  int ksb = blockIdx.z;  // kt range [ksb*32, ksb*32+32)
  int tid = threadIdx.x, lane = tid & 63, wid = tid >> 6;
  int cg = (lane & 7) ^ (lane >> 3);

  const short* baseA[8];
  const short* baseB[4];
  if (wid < 2) {
#pragma unroll
    for (int jj = 0; jj < 8; ++jj) {
      int r = 8 * (wid * 8 + jj) + (lane >> 3);
      baseA[jj] = act + (size_t)(2 * (t0 + r)) * H_DIM + cg * 8;
    }
  } else {
#pragma unroll
    for (int jj = 0; jj < 4; ++jj) {
      int d = d0 + 8 * ((wid - 2) * 4 + jj) + (lane >> 3);
      baseB[jj] = wd + (size_t)d * H_DIM + cg * 8;
    }
  }

  int ml = lane & 15, quad = lane >> 4;
  int m0w = (wid & 1) * 64, n0w = (wid >> 1) * 32;
  f32x4 acc[4][2];
#pragma unroll
  for (int mf = 0; mf < 4; ++mf)
#pragma unroll
    for (int nf = 0; nf < 2; ++nf) acc[mf][nf] = (f32x4){0, 0, 0, 0};

  for (int kt = ksb * 32; kt < ksb * 32 + 32; ++kt) {
    int slot = kt & 1;
    int kh = (kt >> 1) * 64;
    if (wid < 2) {
#pragma unroll
      for (int jj = 0; jj < 8; ++jj)
        llds16(baseA[jj] + (size_t)slot * H_DIM + kh, As + (wid * 8 + jj) * 512);
    } else {
#pragma unroll
      for (int jj = 0; jj < 4; ++jj)
        llds16(baseB[jj] + kh, Bs + ((wid - 2) * 4 + jj) * 512);
    }
    __syncthreads();
#pragma unroll
    for (int ks = 0; ks < 2; ++ks) {
      short8 a[4], b[2];
#pragma unroll
      for (int mf = 0; mf < 4; ++mf) {
        int m = m0w + mf * 16 + ml;
        a[mf] = *(const short8*)&As[m * 64 + (((quad + ks * 4) ^ (ml & 7)) * 8)];
      }
#pragma unroll
      for (int nf = 0; nf < 2; ++nf) {
        int n = n0w + nf * 16 + ml;
        b[nf] = *(const short8*)&Bs[n * 64 + (((quad + ks * 4) ^ (ml & 7)) * 8)];
      }
#pragma unroll
      for (int mf = 0; mf < 4; ++mf)
#pragma unroll
        for (int nf = 0; nf < 2; ++nf)
          acc[mf][nf] = __builtin_amdgcn_mfma_f32_16x16x32_bf16(a[mf], b[nf], acc[mf][nf], 0, 0, 0);
    }
    __syncthreads();
  }

#pragma unroll
  for (int mf = 0; mf < 4; ++mf)
#pragma unroll
    for (int r = 0; r < 4; ++r) {
      int t = t0 + m0w + mf * 16 + quad * 4 + r;
#pragma unroll
      for (int nf = 0; nf < 2; ++nf)
        atomicAdd(&out[(size_t)t * D_DIM + d0 + n0w + nf * 16 + ml], acc[mf][nf][r]);
    }
}

extern "C" void kernel_launch(void* const* d_in, const int* in_sizes, int n_in,
                              void* d_out, int out_size, void* d_ws, size_t ws_size,
                              hipStream_t stream) {
  const float* x = (const float*)d_in[0];
  const float* wr = (const float*)d_in[1];
  const float* wg = (const float*)d_in[2];
  const float* wu = (const float*)d_in[3];
  const float* wd = (const float*)d_in[4];
  float* out = (float*)d_out;

  char* ws = (char*)d_ws;
  size_t off = 0;
  auto alloc = [&](size_t bytes) {
    char* p = ws + off;
    off += (bytes + 255) & ~(size_t)255;
    return p;
  };
  short* xb = (short*)alloc((size_t)N_TOK * D_DIM * 2);
  short* wgb = (short*)alloc((size_t)E_NUM * H_DIM * D_DIM * 2);  // [e*H+h][d]
  short* wub = (short*)alloc((size_t)E_NUM * H_DIM * D_DIM * 2);
  short* wdb = (short*)alloc((size_t)D_DIM * H_DIM * 2);          // [d][h]
  short* act = (short*)alloc((size_t)N_TOK * 2 * H_DIM * 2);      // [2t+slot][H]
  float* probs = (float*)alloc((size_t)N_TOK * E_NUM * 4);
  int* e_cnt = (int*)alloc(256);
  int* e_tok = (int*)alloc((size_t)E_NUM * N_TOK * 4);
  float* e_p = (float*)alloc((size_t)E_NUM * N_TOK * 4);

  hipMemsetAsync(e_cnt, 0, 32, stream);
  hipMemsetAsync(out, 0, (size_t)out_size * 4, stream);

  cvt_kernel<<<N_TOK * D_DIM / 4 / 256, 256, 0, stream>>>(x, xb, N_TOK * D_DIM / 4);
  tcvt_kernel<<<dim3(E_NUM * H_DIM / 32, D_DIM / 32), dim3(32, 8), 0, stream>>>(
      wg, wgb, D_DIM, E_NUM * H_DIM);
  tcvt_kernel<<<dim3(E_NUM * H_DIM / 32, D_DIM / 32), dim3(32, 8), 0, stream>>>(
      wu, wub, D_DIM, E_NUM * H_DIM);
  tcvt_kernel<<<dim3(D_DIM / 32, H_DIM / 32), dim3(32, 8), 0, stream>>>(
      wd, wdb, H_DIM, D_DIM);
  router_kernel<<<N_TOK / 64, 64, 0, stream>>>(x, wr, probs, e_cnt, e_tok, e_p);
  loss_kernel<<<1, 256, 0, stream>>>(probs, out + (size_t)N_TOK * D_DIM);
  moe_gateup_kernel<<<dim3(H_DIM / 64, N_TOK / 128, E_NUM), 256, 0, stream>>>(
      xb, wgb, wub, e_cnt, e_tok, e_p, act);
  down_kernel<<<dim3(D_DIM / 64, N_TOK / 128, 2), 256, 0, stream>>>(act, wdb, out);
}

// Round 4
// 288.527 us; speedup vs baseline: 1.4844x; 1.0434x over previous
//
#include <hip/hip_runtime.h>
#include <hip/hip_bf16.h>

#define N_TOK 4096
#define D_DIM 512
#define E_NUM 8
#define H_DIM 2048

typedef __attribute__((ext_vector_type(8))) short short8;
typedef __attribute__((ext_vector_type(4))) float f32x4;

__device__ inline short f2bs(float f) {
  __hip_bfloat16 h = __float2bfloat16(f);
  return *reinterpret_cast<short*>(&h);
}

// async global->LDS, 16 B per lane; lds dest is wave-uniform base + lane*16
__device__ inline void llds16(const short* g, short* l) {
  __builtin_amdgcn_global_load_lds(
      (const __attribute__((address_space(1))) void*)g,
      (__attribute__((address_space(3))) void*)l, 16, 0, 0);
}

// ---------- fp32 -> bf16 straight conversion (x) ----------
__global__ void cvt_kernel(const float* __restrict__ src, short* __restrict__ dst, int n4) {
  int i = blockIdx.x * blockDim.x + threadIdx.x;
  if (i < n4) {
    float4 v = reinterpret_cast<const float4*>(src)[i];
    short4 o;
    o.x = f2bs(v.x); o.y = f2bs(v.y); o.z = f2bs(v.z); o.w = f2bs(v.w);
    reinterpret_cast<short4*>(dst)[i] = o;
  }
}

// ---------- fp32 [R][C] -> bf16 [C][R] transpose-convert ----------
__global__ void tcvt_kernel(const float* __restrict__ in, short* __restrict__ out, int R, int C) {
  __shared__ float t[32][33];
  int c0 = blockIdx.x * 32, r0 = blockIdx.y * 32;
  int tx = threadIdx.x, ty = threadIdx.y;  // block (32,8)
#pragma unroll
  for (int i = 0; i < 4; ++i)
    t[ty + 8 * i][tx] = in[(size_t)(r0 + ty + 8 * i) * C + c0 + tx];
  __syncthreads();
#pragma unroll
  for (int i = 0; i < 4; ++i)
    out[(size_t)(c0 + ty + 8 * i) * R + r0 + tx] = f2bs(t[tx][ty + 8 * i]);
}

// ---------- router: one token per thread, block-aggregated expert atomics ----------
// e_tok entry encodes token*2 + slot (slot 0 = top-1, slot 1 = top-2)
__global__ void __launch_bounds__(64) router_kernel(
    const float* __restrict__ x, const float* __restrict__ wr,
    float* __restrict__ probs_full, int* __restrict__ e_cnt,
    int* __restrict__ e_tok, float* __restrict__ e_p) {
  __shared__ int h_cnt[E_NUM];
  __shared__ int h_base[E_NUM];
  int tid = threadIdx.x;
  int t = blockIdx.x * 64 + tid;
  if (tid < E_NUM) h_cnt[tid] = 0;
  __syncthreads();

  const float* xr = x + (size_t)t * D_DIM;
  float acc[8] = {0, 0, 0, 0, 0, 0, 0, 0};
#pragma unroll 4
  for (int j = 0; j < D_DIM; j += 4) {
    float4 xv = *(const float4*)(xr + j);
    const float* w0 = wr + (size_t)j * E_NUM;  // wave-uniform -> scalar loads
#pragma unroll
    for (int e = 0; e < 8; ++e) {
      acc[e] += xv.x * w0[e] + xv.y * w0[8 + e] + xv.z * w0[16 + e] + xv.w * w0[24 + e];
    }
  }
  float m = acc[0];
#pragma unroll
  for (int e = 1; e < 8; ++e) m = fmaxf(m, acc[e]);
  float p[8], s = 0.f;
#pragma unroll
  for (int e = 0; e < 8; ++e) { p[e] = expf(acc[e] - m); s += p[e]; }
  float inv = 1.f / s;
#pragma unroll
  for (int e = 0; e < 8; ++e) p[e] *= inv;
  float4 pv0 = {p[0], p[1], p[2], p[3]}, pv1 = {p[4], p[5], p[6], p[7]};
  *(float4*)(probs_full + t * 8) = pv0;
  *(float4*)(probs_full + t * 8 + 4) = pv1;

  int i0 = 0;
#pragma unroll
  for (int e = 1; e < 8; ++e) if (p[e] > p[i0]) i0 = e;
  int i1 = (i0 == 0) ? 1 : 0;
#pragma unroll
  for (int e = 0; e < 8; ++e) if (e != i0 && p[e] > p[i1]) i1 = e;
  float ps = p[i0] + p[i1] + 1e-10f;
  float q0 = p[i0] / ps, q1 = p[i1] / ps;

  int l0 = atomicAdd(&h_cnt[i0], 1);
  int l1 = atomicAdd(&h_cnt[i1], 1);
  __syncthreads();
  if (tid < E_NUM) h_base[tid] = h_cnt[tid] ? atomicAdd(&e_cnt[tid], h_cnt[tid]) : 0;
  __syncthreads();
  int s0 = h_base[i0] + l0;
  e_tok[i0 * N_TOK + s0] = t * 2 + 0; e_p[i0 * N_TOK + s0] = q0;
  int s1 = h_base[i1] + l1;
  e_tok[i1 * N_TOK + s1] = t * 2 + 1; e_p[i1 * N_TOK + s1] = q1;
}

// ---------- load-balance loss ----------
__global__ void __launch_bounds__(256) loss_kernel(const float* __restrict__ probs,
                                                   float* __restrict__ out_loss) {
  __shared__ float sums[8];
  if (threadIdx.x < 8) sums[threadIdx.x] = 0.f;
  __syncthreads();
  float loc[8] = {0, 0, 0, 0, 0, 0, 0, 0};
  for (int t = threadIdx.x; t < N_TOK; t += 256)
#pragma unroll
    for (int e = 0; e < 8; ++e) loc[e] += probs[t * 8 + e];
#pragma unroll
  for (int e = 0; e < 8; ++e) {
    float v = loc[e];
    for (int off = 32; off; off >>= 1) v += __shfl_down(v, off);
    if ((threadIdx.x & 63) == 0) atomicAdd(&sums[e], v);
  }
  __syncthreads();
  if (threadIdx.x == 0) {
    float lb = 0.f;
    for (int e = 0; e < 8; ++e) {
      float pe = sums[e] / (float)N_TOK;
      lb += pe * logf(pe * 8.f + 1e-10f);
    }
    out_loss[0] = 8.f * lb;
  }
}

// ---------- grouped gate/up GEMM (256 tok x 64 h tile, G+U fused) ----------
// writes bf16 act[(2t+slot)][H] = p * silu(g) * u  (non-atomic, each row once)
__global__ void __launch_bounds__(256, 2) moe_gateup_kernel(
    const short* __restrict__ xb, const short* __restrict__ wg,
    const short* __restrict__ wu, const int* __restrict__ e_cnt,
    const int* __restrict__ e_tok, const float* __restrict__ e_p,
    short* __restrict__ act) {
  __shared__ __align__(16) short As[256 * 64];   // 32 KB, [m][chunk^(m&7)]
  __shared__ __align__(16) short Bgs[64 * 64];   // 8 KB
  __shared__ __align__(16) short Bus[64 * 64];   // 8 KB
  __shared__ int s_row[256];
  __shared__ float s_pr[256];

  int e = blockIdx.z;
  int n_e = e_cnt[e];
  int rt = blockIdx.y;
  if (rt * 256 >= n_e) return;
  int h0 = blockIdx.x * 64;
  int tid = threadIdx.x;
  int lane = tid & 63, wid = tid >> 6;

  {
    int r = rt * 256 + tid;
    bool v = r < n_e;
    s_row[tid] = v ? e_tok[e * N_TOK + r] : -1;
    s_pr[tid] = v ? e_p[e * N_TOK + r] : 0.f;
  }
  __syncthreads();

  // staging: each wave loads its 64-row A stripe (8 calls) + 32 rows of B (4 calls)
  int cg = (lane & 7) ^ (lane >> 3);  // swizzled global chunk for this lane
  const short* baseA[8];
  const short* baseB[4];
  short* ldsA = As + (size_t)wid * 64 * 64;
  short* ldsB;
#pragma unroll
  for (int jj = 0; jj < 8; ++jj) {
    int r = wid * 64 + jj * 8 + (lane >> 3);
    int row = s_row[r];
    int t = (row < 0) ? 0 : (row >> 1);
    baseA[jj] = xb + (size_t)t * D_DIM + cg * 8;
  }
  {
    const short* wB = ((wid & 2) ? wu : wg) + (size_t)e * H_DIM * D_DIM;
    int rb = (wid & 1) * 32;
    ldsB = ((wid & 2) ? Bus : Bgs) + rb * 64;
#pragma unroll
    for (int jj = 0; jj < 4; ++jj) {
      int h = h0 + rb + jj * 8 + (lane >> 3);
      baseB[jj] = wB + (size_t)h * D_DIM + cg * 8;
    }
  }

  int ml = lane & 15, quad = lane >> 4;
  int m0w = wid * 64;
  f32x4 accG[4][4], accU[4][4];
#pragma unroll
  for (int mf = 0; mf < 4; ++mf)
#pragma unroll
    for (int nf = 0; nf < 4; ++nf) {
      accG[mf][nf] = (f32x4){0, 0, 0, 0};
      accU[mf][nf] = (f32x4){0, 0, 0, 0};
    }

  for (int kt = 0; kt < D_DIM / 64; ++kt) {
    int kb = kt * 64;
#pragma unroll
    for (int jj = 0; jj < 8; ++jj)
      llds16(baseA[jj] + kb, ldsA + jj * 8 * 64);
#pragma unroll
    for (int jj = 0; jj < 4; ++jj)
      llds16(baseB[jj] + kb, ldsB + jj * 8 * 64);
    __syncthreads();
#pragma unroll
    for (int ks = 0; ks < 2; ++ks) {
      int cs = ((quad + ks * 4) ^ (ml & 7)) * 8;
      short8 a[4], bg[4], bu[4];
#pragma unroll
      for (int mf = 0; mf < 4; ++mf)
        a[mf] = *(const short8*)&As[(m0w + mf * 16 + ml) * 64 + cs];
#pragma unroll
      for (int nf = 0; nf < 4; ++nf) {
        bg[nf] = *(const short8*)&Bgs[(nf * 16 + ml) * 64 + cs];
        bu[nf] = *(const short8*)&Bus[(nf * 16 + ml) * 64 + cs];
      }
#pragma unroll
      for (int mf = 0; mf < 4; ++mf)
#pragma unroll
        for (int nf = 0; nf < 4; ++nf) {
          accG[mf][nf] = __builtin_amdgcn_mfma_f32_16x16x32_bf16(a[mf], bg[nf], accG[mf][nf], 0, 0, 0);
          accU[mf][nf] = __builtin_amdgcn_mfma_f32_16x16x32_bf16(a[mf], bu[nf], accU[mf][nf], 0, 0, 0);
        }
    }
    __syncthreads();
  }

#pragma unroll
  for (int mf = 0; mf < 4; ++mf)
#pragma unroll
    for (int r = 0; r < 4; ++r) {
      int rl = m0w + mf * 16 + quad * 4 + r;
      int arow = s_row[rl];
      if (arow >= 0) {
        float pr = s_pr[rl];
#pragma unroll
        for (int nf = 0; nf < 4; ++nf) {
          float g = accG[mf][nf][r], u = accU[mf][nf][r];
          float val = pr * (g / (1.f + __expf(-g))) * u;
          act[(size_t)arow * H_DIM + h0 + nf * 16 + ml] = f2bs(val);
        }
      }
    }
}

// ---------- down GEMM: out[t] = (act[2t] + act[2t+1]) @ wd, K=4096 view ----------
// 128x128 tile, Ksplit=4 across blockIdx.z; fp32 atomicAdd into zeroed out
__global__ void __launch_bounds__(256, 3) down_kernel(
    const short* __restrict__ act, const short* __restrict__ wd,
    float* __restrict__ out) {
  __shared__ __align__(16) short As[128 * 64];  // 16 KB
  __shared__ __align__(16) short Bs[128 * 64];  // 16 KB
  int d0 = blockIdx.x * 128;
  int t0 = blockIdx.y * 128;
  int ksb = blockIdx.z;  // kt range [ksb*16, ksb*16+16)
  int tid = threadIdx.x, lane = tid & 63, wid = tid >> 6;
  int cg = (lane & 7) ^ (lane >> 3);

  const short* baseA[4];
  const short* baseB[4];
  short* ldsA = As + (size_t)wid * 32 * 64;
  short* ldsB = Bs + (size_t)wid * 32 * 64;
#pragma unroll
  for (int jj = 0; jj < 4; ++jj) {
    int r = wid * 32 + jj * 8 + (lane >> 3);
    baseA[jj] = act + (size_t)(2 * (t0 + r)) * H_DIM + cg * 8;
    int d = d0 + wid * 32 + jj * 8 + (lane >> 3);
    baseB[jj] = wd + (size_t)d * H_DIM + cg * 8;
  }

  int ml = lane & 15, quad = lane >> 4;
  int m0w = (wid & 1) * 64, n0w = (wid >> 1) * 64;
  f32x4 acc[4][4];
#pragma unroll
  for (int mf = 0; mf < 4; ++mf)
#pragma unroll
    for (int nf = 0; nf < 4; ++nf) acc[mf][nf] = (f32x4){0, 0, 0, 0};

  for (int kt = ksb * 16; kt < ksb * 16 + 16; ++kt) {
    size_t offA = (size_t)(kt & 1) * H_DIM + (kt >> 1) * 64;
    int offB = (kt >> 1) * 64;
#pragma unroll
    for (int jj = 0; jj < 4; ++jj) {
      llds16(baseA[jj] + offA, ldsA + jj * 8 * 64);
      llds16(baseB[jj] + offB, ldsB + jj * 8 * 64);
    }
    __syncthreads();
#pragma unroll
    for (int ks = 0; ks < 2; ++ks) {
      int cs = ((quad + ks * 4) ^ (ml & 7)) * 8;
      short8 a[4], b[4];
#pragma unroll
      for (int mf = 0; mf < 4; ++mf)
        a[mf] = *(const short8*)&As[(m0w + mf * 16 + ml) * 64 + cs];
#pragma unroll
      for (int nf = 0; nf < 4; ++nf)
        b[nf] = *(const short8*)&Bs[(n0w + nf * 16 + ml) * 64 + cs];
#pragma unroll
      for (int mf = 0; mf < 4; ++mf)
#pragma unroll
        for (int nf = 0; nf < 4; ++nf)
          acc[mf][nf] = __builtin_amdgcn_mfma_f32_16x16x32_bf16(a[mf], b[nf], acc[mf][nf], 0, 0, 0);
    }
    __syncthreads();
  }

#pragma unroll
  for (int mf = 0; mf < 4; ++mf)
#pragma unroll
    for (int r = 0; r < 4; ++r) {
      int t = t0 + m0w + mf * 16 + quad * 4 + r;
#pragma unroll
      for (int nf = 0; nf < 4; ++nf)
        atomicAdd(&out[(size_t)t * D_DIM + d0 + n0w + nf * 16 + ml], acc[mf][nf][r]);
    }
}

extern "C" void kernel_launch(void* const* d_in, const int* in_sizes, int n_in,
                              void* d_out, int out_size, void* d_ws, size_t ws_size,
                              hipStream_t stream) {
  const float* x = (const float*)d_in[0];
  const float* wr = (const float*)d_in[1];
  const float* wg = (const float*)d_in[2];
  const float* wu = (const float*)d_in[3];
  const float* wd = (const float*)d_in[4];
  float* out = (float*)d_out;

  char* ws = (char*)d_ws;
  size_t off = 0;
  auto alloc = [&](size_t bytes) {
    char* p = ws + off;
    off += (bytes + 255) & ~(size_t)255;
    return p;
  };
  short* xb = (short*)alloc((size_t)N_TOK * D_DIM * 2);
  short* wgb = (short*)alloc((size_t)E_NUM * H_DIM * D_DIM * 2);  // [e*H+h][d]
  short* wub = (short*)alloc((size_t)E_NUM * H_DIM * D_DIM * 2);
  short* wdb = (short*)alloc((size_t)D_DIM * H_DIM * 2);          // [d][h]
  short* act = (short*)alloc((size_t)N_TOK * 2 * H_DIM * 2);      // [2t+slot][H]
  float* probs = (float*)alloc((size_t)N_TOK * E_NUM * 4);
  int* e_cnt = (int*)alloc(256);
  int* e_tok = (int*)alloc((size_t)E_NUM * N_TOK * 4);
  float* e_p = (float*)alloc((size_t)E_NUM * N_TOK * 4);

  hipMemsetAsync(e_cnt, 0, 32, stream);
  hipMemsetAsync(out, 0, (size_t)out_size * 4, stream);

  cvt_kernel<<<N_TOK * D_DIM / 4 / 256, 256, 0, stream>>>(x, xb, N_TOK * D_DIM / 4);
  tcvt_kernel<<<dim3(E_NUM * H_DIM / 32, D_DIM / 32), dim3(32, 8), 0, stream>>>(
      wg, wgb, D_DIM, E_NUM * H_DIM);
  tcvt_kernel<<<dim3(E_NUM * H_DIM / 32, D_DIM / 32), dim3(32, 8), 0, stream>>>(
      wu, wub, D_DIM, E_NUM * H_DIM);
  tcvt_kernel<<<dim3(D_DIM / 32, H_DIM / 32), dim3(32, 8), 0, stream>>>(
      wd, wdb, H_DIM, D_DIM);
  router_kernel<<<N_TOK / 64, 64, 0, stream>>>(x, wr, probs, e_cnt, e_tok, e_p);
  loss_kernel<<<1, 256, 0, stream>>>(probs, out + (size_t)N_TOK * D_DIM);
  moe_gateup_kernel<<<dim3(H_DIM / 64, N_TOK / 256, E_NUM), 256, 0, stream>>>(
      xb, wgb, wub, e_cnt, e_tok, e_p, act);
  down_kernel<<<dim3(D_DIM / 128, N_TOK / 128, 4), 256, 0, stream>>>(act, wdb, out);
}

// Round 5
// 247.573 us; speedup vs baseline: 1.7299x; 1.1654x over previous
//
#include <hip/hip_runtime.h>
#include <hip/hip_bf16.h>

#define N_TOK 4096
#define D_DIM 512
#define E_NUM 8
#define H_DIM 2048

typedef __attribute__((ext_vector_type(8))) short short8;
typedef __attribute__((ext_vector_type(4))) float f32x4;

__device__ inline short f2bs(float f) {
  __hip_bfloat16 h = __float2bfloat16(f);
  return *reinterpret_cast<short*>(&h);
}

// async global->LDS, 16 B per lane; lds dest is wave-uniform base + lane*16
__device__ inline void llds16(const short* g, short* l) {
  __builtin_amdgcn_global_load_lds(
      (const __attribute__((address_space(1))) void*)g,
      (__attribute__((address_space(3))) void*)l, 16, 0, 0);
}

// ---------- fused prep: wg/wu/wd transpose-convert + zero out + zero counters ----------
// unit u: [0,8192) wg tiles, [8192,16384) wu, [16384,17408) wd,
//         [17408,17920) zero out, 17920 zero counters
__global__ void __launch_bounds__(256) prep_kernel(
    const float* __restrict__ wg, const float* __restrict__ wu,
    const float* __restrict__ wd, short* __restrict__ wgb,
    short* __restrict__ wub, short* __restrict__ wdb,
    float* __restrict__ out, int* __restrict__ e_cnt,
    float* __restrict__ loss_acc, int* __restrict__ loss_cnt) {
  int u = blockIdx.x;
  int tid = threadIdx.x;
  if (u < 17408) {
    __shared__ float tbuf[32][33];
    const float* in;
    short* op;
    int R, C, c0, r0;
    if (u < 16384) {
      in = (u < 8192) ? wg : wu;
      op = (u < 8192) ? wgb : wub;
      int v = u & 8191;
      R = D_DIM; C = E_NUM * H_DIM;
      c0 = (v & 511) * 32; r0 = (v >> 9) * 32;
    } else {
      in = wd; op = wdb;
      int v = u - 16384;
      R = H_DIM; C = D_DIM;
      c0 = (v & 15) * 32; r0 = (v >> 4) * 32;
    }
    int tx = tid & 31, ty = tid >> 5;
#pragma unroll
    for (int i = 0; i < 4; ++i)
      tbuf[ty + 8 * i][tx] = in[(size_t)(r0 + ty + 8 * i) * C + c0 + tx];
    __syncthreads();
#pragma unroll
    for (int i = 0; i < 4; ++i)
      op[(size_t)(c0 + ty + 8 * i) * R + r0 + tx] = f2bs(tbuf[tx][ty + 8 * i]);
  } else if (u < 17920) {
    int v = u - 17408;
    float4* dst = (float4*)(out + (size_t)v * 4096);  // 512 * 4096 = N_TOK*D_DIM
    float4 z = {0.f, 0.f, 0.f, 0.f};
#pragma unroll
    for (int i = 0; i < 4; ++i) dst[tid + 256 * i] = z;
  } else {
    if (tid < 8) { e_cnt[tid] = 0; loss_acc[tid] = 0.f; }
    if (tid == 8) *loss_cnt = 0;
  }
}

// ---------- fused router: x->bf16 cvt + fp32 logits + softmax/top2 + lb-loss ----------
// 4 lanes per token; 64 tokens per 256-thread block; grid = 64
// e_tok entry encodes token*2 + slot
__global__ void __launch_bounds__(256) router_kernel(
    const float* __restrict__ x, const float* __restrict__ wr,
    short* __restrict__ xb, int* __restrict__ e_cnt,
    int* __restrict__ e_tok, float* __restrict__ e_p,
    float* __restrict__ loss_acc, int* __restrict__ loss_cnt,
    float* __restrict__ out_loss) {
  __shared__ float wr_lds[D_DIM * E_NUM];  // 16 KB
  __shared__ int h_cnt[E_NUM];
  __shared__ int h_base[E_NUM];
  __shared__ float psum[E_NUM];
  int tid = threadIdx.x;

  for (int i = tid; i < D_DIM * E_NUM / 4; i += 256)
    *(float4*)&wr_lds[i * 4] = *(const float4*)&wr[i * 4];
  if (tid < E_NUM) { h_cnt[tid] = 0; psum[tid] = 0.f; }
  __syncthreads();

  int r = tid >> 2, pp = tid & 3;
  int t = blockIdx.x * 64 + r;
  const float* xr = x + (size_t)t * D_DIM + pp * 128;
  short* xw = xb + (size_t)t * D_DIM + pp * 128;
  float acc[8] = {0, 0, 0, 0, 0, 0, 0, 0};
#pragma unroll 4
  for (int j = 0; j < 128; j += 4) {
    float4 xv = *(const float4*)(xr + j);
    short4 o;
    o.x = f2bs(xv.x); o.y = f2bs(xv.y); o.z = f2bs(xv.z); o.w = f2bs(xv.w);
    *(short4*)(xw + j) = o;
    const float* w = &wr_lds[(pp * 128 + j) * E_NUM];
#pragma unroll
    for (int e = 0; e < 8; ++e)
      acc[e] += xv.x * w[e] + xv.y * w[8 + e] + xv.z * w[16 + e] + xv.w * w[24 + e];
  }
#pragma unroll
  for (int e = 0; e < 8; ++e) {
    acc[e] += __shfl_xor(acc[e], 1);
    acc[e] += __shfl_xor(acc[e], 2);
  }

  bool leader = (pp == 0);
  int i0 = 0, i1 = 1, l0 = 0, l1 = 0;
  float q0 = 0.f, q1 = 0.f;
  if (leader) {
    float m = acc[0];
#pragma unroll
    for (int e = 1; e < 8; ++e) m = fmaxf(m, acc[e]);
    float p[8], s = 0.f;
#pragma unroll
    for (int e = 0; e < 8; ++e) { p[e] = expf(acc[e] - m); s += p[e]; }
    float inv = 1.f / s;
#pragma unroll
    for (int e = 0; e < 8; ++e) {
      p[e] *= inv;
      atomicAdd(&psum[e], p[e]);
    }
    i0 = 0;
#pragma unroll
    for (int e = 1; e < 8; ++e) if (p[e] > p[i0]) i0 = e;
    i1 = (i0 == 0) ? 1 : 0;
#pragma unroll
    for (int e = 0; e < 8; ++e) if (e != i0 && p[e] > p[i1]) i1 = e;
    float ps = p[i0] + p[i1] + 1e-10f;
    q0 = p[i0] / ps; q1 = p[i1] / ps;
    l0 = atomicAdd(&h_cnt[i0], 1);
    l1 = atomicAdd(&h_cnt[i1], 1);
  }
  __syncthreads();
  if (tid < E_NUM) {
    h_base[tid] = h_cnt[tid] ? atomicAdd(&e_cnt[tid], h_cnt[tid]) : 0;
    atomicAdd(&loss_acc[tid], psum[tid]);  // device-scope
  }
  __syncthreads();
  if (leader) {
    int s0 = h_base[i0] + l0;
    e_tok[i0 * N_TOK + s0] = t * 2 + 0; e_p[i0 * N_TOK + s0] = q0;
    int s1 = h_base[i1] + l1;
    e_tok[i1 * N_TOK + s1] = t * 2 + 1; e_p[i1 * N_TOK + s1] = q1;
  }
  __threadfence();
  __syncthreads();
  if (tid == 0) {
    int c = atomicAdd(loss_cnt, 1);
    if (c == 63) {  // last block: all loss_acc adds visible (fence + atomic RMW reads)
      float lb = 0.f;
#pragma unroll
      for (int e = 0; e < 8; ++e) {
        float pe = atomicAdd(&loss_acc[e], 0.f) / (float)N_TOK;
        lb += pe * logf(pe * 8.f + 1e-10f);
      }
      out_loss[0] = 8.f * lb;
    }
  }
}

// ---------- grouped gate/up GEMM (256 tok x 64 h tile, G+U fused) ----------
// writes bf16 act[(2t+slot)][H] = p * silu(g) * u  (non-atomic, each row once)
__global__ void __launch_bounds__(256, 2) moe_gateup_kernel(
    const short* __restrict__ xb, const short* __restrict__ wg,
    const short* __restrict__ wu, const int* __restrict__ e_cnt,
    const int* __restrict__ e_tok, const float* __restrict__ e_p,
    short* __restrict__ act) {
  __shared__ __align__(16) short As[256 * 64];   // 32 KB, [m][chunk^(m&7)]
  __shared__ __align__(16) short Bgs[64 * 64];   // 8 KB
  __shared__ __align__(16) short Bus[64 * 64];   // 8 KB
  __shared__ int s_row[256];
  __shared__ float s_pr[256];

  int e = blockIdx.z;
  int n_e = e_cnt[e];
  int rt = blockIdx.y;
  if (rt * 256 >= n_e) return;
  int h0 = blockIdx.x * 64;
  int tid = threadIdx.x;
  int lane = tid & 63, wid = tid >> 6;

  {
    int r = rt * 256 + tid;
    bool v = r < n_e;
    s_row[tid] = v ? e_tok[e * N_TOK + r] : -1;
    s_pr[tid] = v ? e_p[e * N_TOK + r] : 0.f;
  }
  __syncthreads();

  int cg = (lane & 7) ^ (lane >> 3);  // swizzled global chunk for this lane
  const short* baseA[8];
  const short* baseB[4];
  short* ldsA = As + (size_t)wid * 64 * 64;
  short* ldsB;
#pragma unroll
  for (int jj = 0; jj < 8; ++jj) {
    int r = wid * 64 + jj * 8 + (lane >> 3);
    int row = s_row[r];
    int t = (row < 0) ? 0 : (row >> 1);
    baseA[jj] = xb + (size_t)t * D_DIM + cg * 8;
  }
  {
    const short* wB = ((wid & 2) ? wu : wg) + (size_t)e * H_DIM * D_DIM;
    int rb = (wid & 1) * 32;
    ldsB = ((wid & 2) ? Bus : Bgs) + rb * 64;
#pragma unroll
    for (int jj = 0; jj < 4; ++jj) {
      int h = h0 + rb + jj * 8 + (lane >> 3);
      baseB[jj] = wB + (size_t)h * D_DIM + cg * 8;
    }
  }

  int ml = lane & 15, quad = lane >> 4;
  int m0w = wid * 64;
  f32x4 accG[4][4], accU[4][4];
#pragma unroll
  for (int mf = 0; mf < 4; ++mf)
#pragma unroll
    for (int nf = 0; nf < 4; ++nf) {
      accG[mf][nf] = (f32x4){0, 0, 0, 0};
      accU[mf][nf] = (f32x4){0, 0, 0, 0};
    }

  for (int kt = 0; kt < D_DIM / 64; ++kt) {
    int kb = kt * 64;
#pragma unroll
    for (int jj = 0; jj < 8; ++jj)
      llds16(baseA[jj] + kb, ldsA + jj * 8 * 64);
#pragma unroll
    for (int jj = 0; jj < 4; ++jj)
      llds16(baseB[jj] + kb, ldsB + jj * 8 * 64);
    __syncthreads();
#pragma unroll
    for (int ks = 0; ks < 2; ++ks) {
      int cs = ((quad + ks * 4) ^ (ml & 7)) * 8;
      short8 a[4], bg[4], bu[4];
#pragma unroll
      for (int mf = 0; mf < 4; ++mf)
        a[mf] = *(const short8*)&As[(m0w + mf * 16 + ml) * 64 + cs];
#pragma unroll
      for (int nf = 0; nf < 4; ++nf) {
        bg[nf] = *(const short8*)&Bgs[(nf * 16 + ml) * 64 + cs];
        bu[nf] = *(const short8*)&Bus[(nf * 16 + ml) * 64 + cs];
      }
#pragma unroll
      for (int mf = 0; mf < 4; ++mf)
#pragma unroll
        for (int nf = 0; nf < 4; ++nf) {
          accG[mf][nf] = __builtin_amdgcn_mfma_f32_16x16x32_bf16(a[mf], bg[nf], accG[mf][nf], 0, 0, 0);
          accU[mf][nf] = __builtin_amdgcn_mfma_f32_16x16x32_bf16(a[mf], bu[nf], accU[mf][nf], 0, 0, 0);
        }
    }
    __syncthreads();
  }

#pragma unroll
  for (int mf = 0; mf < 4; ++mf)
#pragma unroll
    for (int r = 0; r < 4; ++r) {
      int rl = m0w + mf * 16 + quad * 4 + r;
      int arow = s_row[rl];
      if (arow >= 0) {
        float pr = s_pr[rl];
#pragma unroll
        for (int nf = 0; nf < 4; ++nf) {
          float g = accG[mf][nf][r], u = accU[mf][nf][r];
          float val = pr * (g / (1.f + __expf(-g))) * u;
          act[(size_t)arow * H_DIM + h0 + nf * 16 + ml] = f2bs(val);
        }
      }
    }
}

// ---------- down GEMM: out[t] = (act[2t] + act[2t+1]) @ wd, K=4096 view ----------
// 128x128 tile, Ksplit=4 across blockIdx.z; fp32 atomicAdd into zeroed out
__global__ void __launch_bounds__(256, 3) down_kernel(
    const short* __restrict__ act, const short* __restrict__ wd,
    float* __restrict__ out) {
  __shared__ __align__(16) short As[128 * 64];  // 16 KB
  __shared__ __align__(16) short Bs[128 * 64];  // 16 KB
  int d0 = blockIdx.x * 128;
  int t0 = blockIdx.y * 128;
  int ksb = blockIdx.z;  // kt range [ksb*16, ksb*16+16)
  int tid = threadIdx.x, lane = tid & 63, wid = tid >> 6;
  int cg = (lane & 7) ^ (lane >> 3);

  const short* baseA[4];
  const short* baseB[4];
  short* ldsA = As + (size_t)wid * 32 * 64;
  short* ldsB = Bs + (size_t)wid * 32 * 64;
#pragma unroll
  for (int jj = 0; jj < 4; ++jj) {
    int r = wid * 32 + jj * 8 + (lane >> 3);
    baseA[jj] = act + (size_t)(2 * (t0 + r)) * H_DIM + cg * 8;
    int d = d0 + wid * 32 + jj * 8 + (lane >> 3);
    baseB[jj] = wd + (size_t)d * H_DIM + cg * 8;
  }

  int ml = lane & 15, quad = lane >> 4;
  int m0w = (wid & 1) * 64, n0w = (wid >> 1) * 64;
  f32x4 acc[4][4];
#pragma unroll
  for (int mf = 0; mf < 4; ++mf)
#pragma unroll
    for (int nf = 0; nf < 4; ++nf) acc[mf][nf] = (f32x4){0, 0, 0, 0};

  for (int kt = ksb * 16; kt < ksb * 16 + 16; ++kt) {
    size_t offA = (size_t)(kt & 1) * H_DIM + (kt >> 1) * 64;
    int offB = (kt >> 1) * 64;
#pragma unroll
    for (int jj = 0; jj < 4; ++jj) {
      llds16(baseA[jj] + offA, ldsA + jj * 8 * 64);
      llds16(baseB[jj] + offB, ldsB + jj * 8 * 64);
    }
    __syncthreads();
#pragma unroll
    for (int ks = 0; ks < 2; ++ks) {
      int cs = ((quad + ks * 4) ^ (ml & 7)) * 8;
      short8 a[4], b[4];
#pragma unroll
      for (int mf = 0; mf < 4; ++mf)
        a[mf] = *(const short8*)&As[(m0w + mf * 16 + ml) * 64 + cs];
#pragma unroll
      for (int nf = 0; nf < 4; ++nf)
        b[nf] = *(const short8*)&Bs[(n0w + nf * 16 + ml) * 64 + cs];
#pragma unroll
      for (int mf = 0; mf < 4; ++mf)
#pragma unroll
        for (int nf = 0; nf < 4; ++nf)
          acc[mf][nf] = __builtin_amdgcn_mfma_f32_16x16x32_bf16(a[mf], b[nf], acc[mf][nf], 0, 0, 0);
    }
    __syncthreads();
  }

#pragma unroll
  for (int mf = 0; mf < 4; ++mf)
#pragma unroll
    for (int r = 0; r < 4; ++r) {
      int t = t0 + m0w + mf * 16 + quad * 4 + r;
#pragma unroll
      for (int nf = 0; nf < 4; ++nf)
        atomicAdd(&out[(size_t)t * D_DIM + d0 + n0w + nf * 16 + ml], acc[mf][nf][r]);
    }
}

extern "C" void kernel_launch(void* const* d_in, const int* in_sizes, int n_in,
                              void* d_out, int out_size, void* d_ws, size_t ws_size,
                              hipStream_t stream) {
  const float* x = (const float*)d_in[0];
  const float* wr = (const float*)d_in[1];
  const float* wg = (const float*)d_in[2];
  const float* wu = (const float*)d_in[3];
  const float* wd = (const float*)d_in[4];
  float* out = (float*)d_out;

  char* ws = (char*)d_ws;
  size_t off = 0;
  auto alloc = [&](size_t bytes) {
    char* p = ws + off;
    off += (bytes + 255) & ~(size_t)255;
    return p;
  };
  short* xb = (short*)alloc((size_t)N_TOK * D_DIM * 2);
  short* wgb = (short*)alloc((size_t)E_NUM * H_DIM * D_DIM * 2);  // [e*H+h][d]
  short* wub = (short*)alloc((size_t)E_NUM * H_DIM * D_DIM * 2);
  short* wdb = (short*)alloc((size_t)D_DIM * H_DIM * 2);          // [d][h]
  short* act = (short*)alloc((size_t)N_TOK * 2 * H_DIM * 2);      // [2t+slot][H]
  int* e_cnt = (int*)alloc(256);
  int* e_tok = (int*)alloc((size_t)E_NUM * N_TOK * 4);
  float* e_p = (float*)alloc((size_t)E_NUM * N_TOK * 4);
  float* loss_acc = (float*)alloc(256);
  int* loss_cnt = (int*)alloc(256);

  prep_kernel<<<17921, 256, 0, stream>>>(wg, wu, wd, wgb, wub, wdb, out,
                                         e_cnt, loss_acc, loss_cnt);
  router_kernel<<<N_TOK / 64, 256, 0, stream>>>(x, wr, xb, e_cnt, e_tok, e_p,
                                                loss_acc, loss_cnt,
                                                out + (size_t)N_TOK * D_DIM);
  moe_gateup_kernel<<<dim3(H_DIM / 64, N_TOK / 256, E_NUM), 256, 0, stream>>>(
      xb, wgb, wub, e_cnt, e_tok, e_p, act);
  down_kernel<<<dim3(D_DIM / 128, N_TOK / 128, 4), 256, 0, stream>>>(act, wdb, out);
}

// Round 6
// 242.261 us; speedup vs baseline: 1.7679x; 1.0219x over previous
//
#include <hip/hip_runtime.h>
#include <hip/hip_bf16.h>

#define N_TOK 4096
#define D_DIM 512
#define E_NUM 8
#define H_DIM 2048

typedef __attribute__((ext_vector_type(8))) short short8;
typedef __attribute__((ext_vector_type(4))) float f32x4;

__device__ inline short f2bs(float f) {
  __hip_bfloat16 h = __float2bfloat16(f);
  return *reinterpret_cast<short*>(&h);
}

// async global->LDS, 16 B per lane; lds dest is wave-uniform base + lane*16
__device__ inline void llds16(const short* g, short* l) {
  __builtin_amdgcn_global_load_lds(
      (const __attribute__((address_space(1))) void*)g,
      (__attribute__((address_space(3))) void*)l, 16, 0, 0);
}

// ---------- fused prep: wg/wu/wd transpose-convert + zero counters ----------
// unit u: [0,8192) wg tiles, [8192,16384) wu, [16384,17408) wd, 17408 counters
__global__ void __launch_bounds__(256) prep_kernel(
    const float* __restrict__ wg, const float* __restrict__ wu,
    const float* __restrict__ wd, short* __restrict__ wgb,
    short* __restrict__ wub, short* __restrict__ wdb,
    int* __restrict__ e_cnt, float* __restrict__ loss_acc,
    int* __restrict__ loss_cnt) {
  int u = blockIdx.x;
  int tid = threadIdx.x;
  if (u < 17408) {
    __shared__ float tbuf[32][33];
    const float* in;
    short* op;
    int R, C, c0, r0;
    if (u < 16384) {
      in = (u < 8192) ? wg : wu;
      op = (u < 8192) ? wgb : wub;
      int v = u & 8191;
      R = D_DIM; C = E_NUM * H_DIM;
      c0 = (v & 511) * 32; r0 = (v >> 9) * 32;
    } else {
      in = wd; op = wdb;
      int v = u - 16384;
      R = H_DIM; C = D_DIM;
      c0 = (v & 15) * 32; r0 = (v >> 4) * 32;
    }
    int tx = tid & 31, ty = tid >> 5;
#pragma unroll
    for (int i = 0; i < 4; ++i)
      tbuf[ty + 8 * i][tx] = in[(size_t)(r0 + ty + 8 * i) * C + c0 + tx];
    __syncthreads();
#pragma unroll
    for (int i = 0; i < 4; ++i)
      op[(size_t)(c0 + ty + 8 * i) * R + r0 + tx] = f2bs(tbuf[tx][ty + 8 * i]);
  } else {
    if (tid < 8) { e_cnt[tid] = 0; loss_acc[tid] = 0.f; }
    if (tid == 8) *loss_cnt = 0;
  }
}

// ---------- fused router: x->bf16 cvt + fp32 logits + softmax/top2 + lb-loss ----------
// 8 lanes per token; 32 tokens per 256-thread block; grid = 128
// e_tok entry encodes token*2 + slot
__global__ void __launch_bounds__(256) router_kernel(
    const float* __restrict__ x, const float* __restrict__ wr,
    short* __restrict__ xb, int* __restrict__ e_cnt,
    int* __restrict__ e_tok, float* __restrict__ e_p,
    float* __restrict__ loss_acc, int* __restrict__ loss_cnt,
    float* __restrict__ out_loss) {
  __shared__ float wr_lds[D_DIM * 9];  // stride-9 pad: kills 8-way bank conflict
  __shared__ int h_cnt[E_NUM];
  __shared__ int h_base[E_NUM];
  __shared__ float psum[E_NUM];
  int tid = threadIdx.x;

  for (int i = tid; i < D_DIM * E_NUM; i += 256)
    wr_lds[(i >> 3) * 9 + (i & 7)] = wr[i];
  if (tid < E_NUM) { h_cnt[tid] = 0; psum[tid] = 0.f; }
  __syncthreads();

  int r = tid >> 3, pp = tid & 7;
  int t = blockIdx.x * 32 + r;
  const float* xr0 = x + (size_t)t * D_DIM;
  short* xw0 = xb + (size_t)t * D_DIM;
  float acc[8] = {0, 0, 0, 0, 0, 0, 0, 0};
#pragma unroll 4
  for (int j = 0; j < 16; ++j) {
    int d = j * 32 + pp * 4;  // token's 8 lanes cover 32 consecutive floats
    float4 xv = *(const float4*)(xr0 + d);
    short4 o;
    o.x = f2bs(xv.x); o.y = f2bs(xv.y); o.z = f2bs(xv.z); o.w = f2bs(xv.w);
    *(short4*)(xw0 + d) = o;
    const float* w = &wr_lds[d * 9];
#pragma unroll
    for (int e = 0; e < 8; ++e)
      acc[e] += xv.x * w[e] + xv.y * w[9 + e] + xv.z * w[18 + e] + xv.w * w[27 + e];
  }
#pragma unroll
  for (int e = 0; e < 8; ++e) {
    acc[e] += __shfl_xor(acc[e], 1);
    acc[e] += __shfl_xor(acc[e], 2);
    acc[e] += __shfl_xor(acc[e], 4);
  }

  bool leader = (pp == 0);
  int i0 = 0, i1 = 1, l0 = 0, l1 = 0;
  float q0 = 0.f, q1 = 0.f;
  if (leader) {
    float m = acc[0];
#pragma unroll
    for (int e = 1; e < 8; ++e) m = fmaxf(m, acc[e]);
    float p[8], s = 0.f;
#pragma unroll
    for (int e = 0; e < 8; ++e) { p[e] = expf(acc[e] - m); s += p[e]; }
    float inv = 1.f / s;
#pragma unroll
    for (int e = 0; e < 8; ++e) {
      p[e] *= inv;
      atomicAdd(&psum[e], p[e]);
    }
    i0 = 0;
#pragma unroll
    for (int e = 1; e < 8; ++e) if (p[e] > p[i0]) i0 = e;
    i1 = (i0 == 0) ? 1 : 0;
#pragma unroll
    for (int e = 0; e < 8; ++e) if (e != i0 && p[e] > p[i1]) i1 = e;
    float ps = p[i0] + p[i1] + 1e-10f;
    q0 = p[i0] / ps; q1 = p[i1] / ps;
    l0 = atomicAdd(&h_cnt[i0], 1);
    l1 = atomicAdd(&h_cnt[i1], 1);
  }
  __syncthreads();
  if (tid < E_NUM) {
    h_base[tid] = h_cnt[tid] ? atomicAdd(&e_cnt[tid], h_cnt[tid]) : 0;
    atomicAdd(&loss_acc[tid], psum[tid]);  // device-scope
  }
  __syncthreads();
  if (leader) {
    int s0 = h_base[i0] + l0;
    e_tok[i0 * N_TOK + s0] = t * 2 + 0; e_p[i0 * N_TOK + s0] = q0;
    int s1 = h_base[i1] + l1;
    e_tok[i1 * N_TOK + s1] = t * 2 + 1; e_p[i1 * N_TOK + s1] = q1;
  }
  __threadfence();
  __syncthreads();
  if (tid == 0) {
    int c = atomicAdd(loss_cnt, 1);
    if (c == 127) {  // last block: all loss_acc adds visible
      float lb = 0.f;
#pragma unroll
      for (int e = 0; e < 8; ++e) {
        float pe = atomicAdd(&loss_acc[e], 0.f) / (float)N_TOK;
        lb += pe * logf(pe * 8.f + 1e-10f);
      }
      out_loss[0] = 8.f * lb;
    }
  }
}

// ---------- grouped gate/up GEMM (256 tok x 64 h tile, G+U fused) ----------
// writes bf16 act[(2t+slot)][H] = p * silu(g) * u  (non-atomic, each row once)
__global__ void __launch_bounds__(256, 2) moe_gateup_kernel(
    const short* __restrict__ xb, const short* __restrict__ wg,
    const short* __restrict__ wu, const int* __restrict__ e_cnt,
    const int* __restrict__ e_tok, const float* __restrict__ e_p,
    short* __restrict__ act) {
  __shared__ __align__(16) short As[256 * 64];   // 32 KB, [m][chunk^(m&7)]
  __shared__ __align__(16) short Bgs[64 * 64];   // 8 KB
  __shared__ __align__(16) short Bus[64 * 64];   // 8 KB
  __shared__ int s_row[256];
  __shared__ float s_pr[256];

  int e = blockIdx.z;
  int n_e = e_cnt[e];
  int rt = blockIdx.y;
  if (rt * 256 >= n_e) return;
  int h0 = blockIdx.x * 64;
  int tid = threadIdx.x;
  int lane = tid & 63, wid = tid >> 6;

  {
    int r = rt * 256 + tid;
    bool v = r < n_e;
    s_row[tid] = v ? e_tok[e * N_TOK + r] : -1;
    s_pr[tid] = v ? e_p[e * N_TOK + r] : 0.f;
  }
  __syncthreads();

  int cg = (lane & 7) ^ (lane >> 3);  // swizzled global chunk for this lane
  const short* baseA[8];
  const short* baseB[4];
  short* ldsA = As + (size_t)wid * 64 * 64;
  short* ldsB;
#pragma unroll
  for (int jj = 0; jj < 8; ++jj) {
    int r = wid * 64 + jj * 8 + (lane >> 3);
    int row = s_row[r];
    int t = (row < 0) ? 0 : (row >> 1);
    baseA[jj] = xb + (size_t)t * D_DIM + cg * 8;
  }
  {
    const short* wB = ((wid & 2) ? wu : wg) + (size_t)e * H_DIM * D_DIM;
    int rb = (wid & 1) * 32;
    ldsB = ((wid & 2) ? Bus : Bgs) + rb * 64;
#pragma unroll
    for (int jj = 0; jj < 4; ++jj) {
      int h = h0 + rb + jj * 8 + (lane >> 3);
      baseB[jj] = wB + (size_t)h * D_DIM + cg * 8;
    }
  }

  int ml = lane & 15, quad = lane >> 4;
  int m0w = wid * 64;
  f32x4 accG[4][4], accU[4][4];
#pragma unroll
  for (int mf = 0; mf < 4; ++mf)
#pragma unroll
    for (int nf = 0; nf < 4; ++nf) {
      accG[mf][nf] = (f32x4){0, 0, 0, 0};
      accU[mf][nf] = (f32x4){0, 0, 0, 0};
    }

  for (int kt = 0; kt < D_DIM / 64; ++kt) {
    int kb = kt * 64;
#pragma unroll
    for (int jj = 0; jj < 8; ++jj)
      llds16(baseA[jj] + kb, ldsA + jj * 8 * 64);
#pragma unroll
    for (int jj = 0; jj < 4; ++jj)
      llds16(baseB[jj] + kb, ldsB + jj * 8 * 64);
    __syncthreads();
#pragma unroll
    for (int ks = 0; ks < 2; ++ks) {
      int cs = ((quad + ks * 4) ^ (ml & 7)) * 8;
      short8 a[4], bg[4], bu[4];
#pragma unroll
      for (int mf = 0; mf < 4; ++mf)
        a[mf] = *(const short8*)&As[(m0w + mf * 16 + ml) * 64 + cs];
#pragma unroll
      for (int nf = 0; nf < 4; ++nf) {
        bg[nf] = *(const short8*)&Bgs[(nf * 16 + ml) * 64 + cs];
        bu[nf] = *(const short8*)&Bus[(nf * 16 + ml) * 64 + cs];
      }
#pragma unroll
      for (int mf = 0; mf < 4; ++mf)
#pragma unroll
        for (int nf = 0; nf < 4; ++nf) {
          accG[mf][nf] = __builtin_amdgcn_mfma_f32_16x16x32_bf16(a[mf], bg[nf], accG[mf][nf], 0, 0, 0);
          accU[mf][nf] = __builtin_amdgcn_mfma_f32_16x16x32_bf16(a[mf], bu[nf], accU[mf][nf], 0, 0, 0);
        }
    }
    __syncthreads();
  }

#pragma unroll
  for (int mf = 0; mf < 4; ++mf)
#pragma unroll
    for (int r = 0; r < 4; ++r) {
      int rl = m0w + mf * 16 + quad * 4 + r;
      int arow = s_row[rl];
      if (arow >= 0) {
        float pr = s_pr[rl];
#pragma unroll
        for (int nf = 0; nf < 4; ++nf) {
          float g = accG[mf][nf][r], u = accU[mf][nf][r];
          float val = pr * (g / (1.f + __expf(-g))) * u;
          act[(size_t)arow * H_DIM + h0 + nf * 16 + ml] = f2bs(val);
        }
      }
    }
}

// ---------- down GEMM: partial[ksb][t][d] = act-slice @ wd (plain stores) ----------
// 128x128 tile, Ksplit=4 across blockIdx.z
__global__ void __launch_bounds__(256, 3) down_kernel(
    const short* __restrict__ act, const short* __restrict__ wd,
    float* __restrict__ partial) {
  __shared__ __align__(16) short As[128 * 64];  // 16 KB
  __shared__ __align__(16) short Bs[128 * 64];  // 16 KB
  int d0 = blockIdx.x * 128;
  int t0 = blockIdx.y * 128;
  int ksb = blockIdx.z;  // kt range [ksb*16, ksb*16+16)
  int tid = threadIdx.x, lane = tid & 63, wid = tid >> 6;
  int cg = (lane & 7) ^ (lane >> 3);

  const short* baseA[4];
  const short* baseB[4];
  short* ldsA = As + (size_t)wid * 32 * 64;
  short* ldsB = Bs + (size_t)wid * 32 * 64;
#pragma unroll
  for (int jj = 0; jj < 4; ++jj) {
    int r = wid * 32 + jj * 8 + (lane >> 3);
    baseA[jj] = act + (size_t)(2 * (t0 + r)) * H_DIM + cg * 8;
    int d = d0 + wid * 32 + jj * 8 + (lane >> 3);
    baseB[jj] = wd + (size_t)d * H_DIM + cg * 8;
  }

  int ml = lane & 15, quad = lane >> 4;
  int m0w = (wid & 1) * 64, n0w = (wid >> 1) * 64;
  f32x4 acc[4][4];
#pragma unroll
  for (int mf = 0; mf < 4; ++mf)
#pragma unroll
    for (int nf = 0; nf < 4; ++nf) acc[mf][nf] = (f32x4){0, 0, 0, 0};

  for (int kt = ksb * 16; kt < ksb * 16 + 16; ++kt) {
    size_t offA = (size_t)(kt & 1) * H_DIM + (kt >> 1) * 64;
    int offB = (kt >> 1) * 64;
#pragma unroll
    for (int jj = 0; jj < 4; ++jj) {
      llds16(baseA[jj] + offA, ldsA + jj * 8 * 64);
      llds16(baseB[jj] + offB, ldsB + jj * 8 * 64);
    }
    __syncthreads();
#pragma unroll
    for (int ks = 0; ks < 2; ++ks) {
      int cs = ((quad + ks * 4) ^ (ml & 7)) * 8;
      short8 a[4], b[4];
#pragma unroll
      for (int mf = 0; mf < 4; ++mf)
        a[mf] = *(const short8*)&As[(m0w + mf * 16 + ml) * 64 + cs];
#pragma unroll
      for (int nf = 0; nf < 4; ++nf)
        b[nf] = *(const short8*)&Bs[(n0w + nf * 16 + ml) * 64 + cs];
#pragma unroll
      for (int mf = 0; mf < 4; ++mf)
#pragma unroll
        for (int nf = 0; nf < 4; ++nf)
          acc[mf][nf] = __builtin_amdgcn_mfma_f32_16x16x32_bf16(a[mf], b[nf], acc[mf][nf], 0, 0, 0);
    }
    __syncthreads();
  }

  float* pout = partial + (size_t)ksb * N_TOK * D_DIM;
#pragma unroll
  for (int mf = 0; mf < 4; ++mf)
#pragma unroll
    for (int r = 0; r < 4; ++r) {
      int t = t0 + m0w + mf * 16 + quad * 4 + r;
#pragma unroll
      for (int nf = 0; nf < 4; ++nf)
        pout[(size_t)t * D_DIM + d0 + n0w + nf * 16 + ml] = acc[mf][nf][r];
    }
}

// ---------- split-K reduce: out = sum of 4 partials ----------
__global__ void __launch_bounds__(256) reduce_kernel(
    const float* __restrict__ partial, float* __restrict__ out) {
  int i = blockIdx.x * 256 + threadIdx.x;  // float4 index
  const int Q = N_TOK * D_DIM / 4;
  const float4* p = (const float4*)partial;
  float4 a = p[i], b = p[i + Q], c = p[i + 2 * Q], d = p[i + 3 * Q];
  float4 r = {a.x + b.x + c.x + d.x, a.y + b.y + c.y + d.y,
              a.z + b.z + c.z + d.z, a.w + b.w + c.w + d.w};
  ((float4*)out)[i] = r;
}

extern "C" void kernel_launch(void* const* d_in, const int* in_sizes, int n_in,
                              void* d_out, int out_size, void* d_ws, size_t ws_size,
                              hipStream_t stream) {
  const float* x = (const float*)d_in[0];
  const float* wr = (const float*)d_in[1];
  const float* wg = (const float*)d_in[2];
  const float* wu = (const float*)d_in[3];
  const float* wd = (const float*)d_in[4];
  float* out = (float*)d_out;

  char* ws = (char*)d_ws;
  size_t off = 0;
  auto alloc = [&](size_t bytes) {
    char* p = ws + off;
    off += (bytes + 255) & ~(size_t)255;
    return p;
  };
  short* xb = (short*)alloc((size_t)N_TOK * D_DIM * 2);
  short* wgb = (short*)alloc((size_t)E_NUM * H_DIM * D_DIM * 2);  // [e*H+h][d]
  short* wub = (short*)alloc((size_t)E_NUM * H_DIM * D_DIM * 2);
  short* wdb = (short*)alloc((size_t)D_DIM * H_DIM * 2);          // [d][h]
  short* act = (short*)alloc((size_t)N_TOK * 2 * H_DIM * 2);      // [2t+slot][H]
  float* partial = (float*)alloc((size_t)4 * N_TOK * D_DIM * 4);  // split-K partials
  int* e_cnt = (int*)alloc(256);
  int* e_tok = (int*)alloc((size_t)E_NUM * N_TOK * 4);
  float* e_p = (float*)alloc((size_t)E_NUM * N_TOK * 4);
  float* loss_acc = (float*)alloc(256);
  int* loss_cnt = (int*)alloc(256);

  prep_kernel<<<17409, 256, 0, stream>>>(wg, wu, wd, wgb, wub, wdb,
                                         e_cnt, loss_acc, loss_cnt);
  router_kernel<<<N_TOK / 32, 256, 0, stream>>>(x, wr, xb, e_cnt, e_tok, e_p,
                                                loss_acc, loss_cnt,
                                                out + (size_t)N_TOK * D_DIM);
  moe_gateup_kernel<<<dim3(H_DIM / 64, N_TOK / 256, E_NUM), 256, 0, stream>>>(
      xb, wgb, wub, e_cnt, e_tok, e_p, act);
  down_kernel<<<dim3(D_DIM / 128, N_TOK / 128, 4), 256, 0, stream>>>(act, wdb, partial);
  reduce_kernel<<<N_TOK * D_DIM / 4 / 256, 256, 0, stream>>>(partial, out);
}

// Round 7
// 215.950 us; speedup vs baseline: 1.9833x; 1.1218x over previous
//
#include <hip/hip_runtime.h>
#include <hip/hip_bf16.h>

#define N_TOK 4096
#define D_DIM 512
#define E_NUM 8
#define H_DIM 2048
#define RB_NUM 256   // router blocks (16 tokens each)

typedef __attribute__((ext_vector_type(8))) short short8;
typedef __attribute__((ext_vector_type(4))) float f32x4;

__device__ inline short f2bs(float f) {
  __hip_bfloat16 h = __float2bfloat16(f);
  return *reinterpret_cast<short*>(&h);
}

// async global->LDS, 16 B per lane; lds dest is wave-uniform base + lane*16
__device__ inline void llds16(const short* g, short* l) {
  __builtin_amdgcn_global_load_lds(
      (const __attribute__((address_space(1))) void*)g,
      (__attribute__((address_space(3))) void*)l, 16, 0, 0);
}

// ---------- fused prep+router ----------
// blocks [0,256): router (16 tokens each, 16 lanes/token, atomic-free buckets)
// blocks [256, 256+16384): wg/wu transpose tiles; [+16384, +17408): wd tiles
__global__ void __launch_bounds__(256) prep_router_kernel(
    const float* __restrict__ wg, const float* __restrict__ wu,
    const float* __restrict__ wd, const float* __restrict__ x,
    const float* __restrict__ wr, short* __restrict__ wgb,
    short* __restrict__ wub, short* __restrict__ wdb, short* __restrict__ xb,
    int* __restrict__ cnt_blk, int* __restrict__ tok_bkt,
    float* __restrict__ p_bkt, float* __restrict__ psum_blk) {
  int u = blockIdx.x;
  int tid = threadIdx.x;

  if (u >= RB_NUM) {
    // ---- transpose-convert part (identical math to R6 prep) ----
    __shared__ float tbuf[32][33];
    int v = u - RB_NUM;
    const float* in;
    short* op;
    int R, C, c0, r0;
    if (v < 16384) {
      in = (v < 8192) ? wg : wu;
      op = (v < 8192) ? wgb : wub;
      int w = v & 8191;
      R = D_DIM; C = E_NUM * H_DIM;
      c0 = (w & 511) * 32; r0 = (w >> 9) * 32;
    } else {
      in = wd; op = wdb;
      int w = v - 16384;
      R = H_DIM; C = D_DIM;
      c0 = (w & 15) * 32; r0 = (w >> 4) * 32;
    }
    int tx = tid & 31, ty = tid >> 5;
#pragma unroll
    for (int i = 0; i < 4; ++i)
      tbuf[ty + 8 * i][tx] = in[(size_t)(r0 + ty + 8 * i) * C + c0 + tx];
    __syncthreads();
#pragma unroll
    for (int i = 0; i < 4; ++i)
      op[(size_t)(c0 + ty + 8 * i) * R + r0 + tx] = f2bs(tbuf[tx][ty + 8 * i]);
    return;
  }

  // ---- router part: 16 tokens, 16 lanes per token ----
  __shared__ float wr_t[E_NUM * D_DIM];  // [e][d], 16 KB
  __shared__ int h_cnt[E_NUM];
  __shared__ float psh[E_NUM];
  int rb = u;
  for (int i = tid; i < D_DIM * E_NUM; i += 256)
    wr_t[(i & 7) * D_DIM + (i >> 3)] = wr[i];  // wr is [d][e]
  if (tid < E_NUM) { h_cnt[tid] = 0; psh[tid] = 0.f; }
  __syncthreads();

  int r = tid >> 4, pp = tid & 15;
  int t = rb * 16 + r;
  const float* xr0 = x + (size_t)t * D_DIM;
  short* xw0 = xb + (size_t)t * D_DIM;
  float acc[8] = {0, 0, 0, 0, 0, 0, 0, 0};
#pragma unroll
  for (int j = 0; j < 8; ++j) {
    int d = j * 64 + pp * 4;  // 16 lanes cover 64 consecutive floats
    float4 xv = *(const float4*)(xr0 + d);
    short4 o;
    o.x = f2bs(xv.x); o.y = f2bs(xv.y); o.z = f2bs(xv.z); o.w = f2bs(xv.w);
    *(short4*)(xw0 + d) = o;
#pragma unroll
    for (int e = 0; e < 8; ++e) {
      float4 w = *(const float4*)&wr_t[e * D_DIM + d];
      acc[e] += xv.x * w.x + xv.y * w.y + xv.z * w.z + xv.w * w.w;
    }
  }
#pragma unroll
  for (int e = 0; e < 8; ++e) {
    acc[e] += __shfl_xor(acc[e], 1);
    acc[e] += __shfl_xor(acc[e], 2);
    acc[e] += __shfl_xor(acc[e], 4);
    acc[e] += __shfl_xor(acc[e], 8);
  }

  if (pp == 0) {
    float m = acc[0];
#pragma unroll
    for (int e = 1; e < 8; ++e) m = fmaxf(m, acc[e]);
    float p[8], s = 0.f;
#pragma unroll
    for (int e = 0; e < 8; ++e) { p[e] = expf(acc[e] - m); s += p[e]; }
    float inv = 1.f / s;
#pragma unroll
    for (int e = 0; e < 8; ++e) {
      p[e] *= inv;
      atomicAdd(&psh[e], p[e]);  // LDS scope
    }
    int i0 = 0;
#pragma unroll
    for (int e = 1; e < 8; ++e) if (p[e] > p[i0]) i0 = e;
    int i1 = (i0 == 0) ? 1 : 0;
#pragma unroll
    for (int e = 0; e < 8; ++e) if (e != i0 && p[e] > p[i1]) i1 = e;
    float ps = p[i0] + p[i1] + 1e-10f;
    float q0 = p[i0] / ps, q1 = p[i1] / ps;
    int l0 = atomicAdd(&h_cnt[i0], 1);  // LDS scope
    int l1 = atomicAdd(&h_cnt[i1], 1);
    tok_bkt[i0 * (RB_NUM * 16) + rb * 16 + l0] = t * 2 + 0;
    p_bkt[i0 * (RB_NUM * 16) + rb * 16 + l0] = q0;
    tok_bkt[i1 * (RB_NUM * 16) + rb * 16 + l1] = t * 2 + 1;
    p_bkt[i1 * (RB_NUM * 16) + rb * 16 + l1] = q1;
  }
  __syncthreads();
  if (tid < E_NUM) {
    cnt_blk[rb * 8 + tid] = h_cnt[tid];   // plain stores, fully owned
    psum_blk[rb * 8 + tid] = psh[tid];
  }
}

// ---------- grouped gate/up GEMM (256 tok x 64 h tile, G+U fused) ----------
// z==8: single loss block; z<8: expert GEMM with prefix-scan row lookup
__global__ void __launch_bounds__(256, 2) moe_gateup_kernel(
    const short* __restrict__ xb, const short* __restrict__ wg,
    const short* __restrict__ wu, const int* __restrict__ cnt_blk,
    const int* __restrict__ tok_bkt, const float* __restrict__ p_bkt,
    const float* __restrict__ psum_blk, short* __restrict__ act,
    float* __restrict__ out_loss) {
  int e = blockIdx.z;
  int tid = threadIdx.x;

  if (e == 8) {  // load-balance loss
    if (blockIdx.x || blockIdx.y) return;
    __shared__ float sums[8];
    if (tid < 8) sums[tid] = 0.f;
    __syncthreads();
#pragma unroll
    for (int ee = 0; ee < 8; ++ee)
      atomicAdd(&sums[ee], psum_blk[tid * 8 + ee]);
    __syncthreads();
    if (tid == 0) {
      float lb = 0.f;
#pragma unroll
      for (int ee = 0; ee < 8; ++ee) {
        float pe = sums[ee] / (float)N_TOK;
        lb += pe * logf(pe * 8.f + 1e-10f);
      }
      out_loss[0] = 8.f * lb;
    }
    return;
  }

  __shared__ __align__(16) short As[256 * 64];   // 32 KB
  __shared__ __align__(16) short Bgs[64 * 64];   // 8 KB
  __shared__ __align__(16) short Bus[64 * 64];   // 8 KB
  __shared__ int scan[256];
  __shared__ int s_row[256];
  __shared__ float s_pr[256];

  // inclusive prefix scan of this expert's per-router-block counts
  scan[tid] = cnt_blk[tid * 8 + e];
  __syncthreads();
  for (int ofs = 1; ofs < 256; ofs <<= 1) {
    int v = (tid >= ofs) ? scan[tid - ofs] : 0;
    __syncthreads();
    scan[tid] += v;
    __syncthreads();
  }
  int n_e = scan[255];
  int rt = blockIdx.y;
  if (rt * 256 >= n_e) return;
  int h0 = blockIdx.x * 64;

  {
    int r = rt * 256 + tid;
    int srow = -1;
    float spr = 0.f;
    if (r < n_e) {
      int lo = 0, hi = 255;  // smallest b with scan[b] > r
      while (lo < hi) { int mid = (lo + hi) >> 1; if (scan[mid] > r) hi = mid; else lo = mid + 1; }
      int prev = lo ? scan[lo - 1] : 0;
      int idx = e * (RB_NUM * 16) + lo * 16 + (r - prev);
      srow = tok_bkt[idx];
      spr = p_bkt[idx];
    }
    s_row[tid] = srow;
    s_pr[tid] = spr;
  }
  __syncthreads();

  int lane = tid & 63, wid = tid >> 6;
  int cg = (lane & 7) ^ (lane >> 3);  // swizzled global chunk for this lane
  const short* baseA[8];
  const short* baseB[4];
  short* ldsA = As + (size_t)wid * 64 * 64;
  short* ldsB;
#pragma unroll
  for (int jj = 0; jj < 8; ++jj) {
    int r = wid * 64 + jj * 8 + (lane >> 3);
    int row = s_row[r];
    int t = (row < 0) ? 0 : (row >> 1);
    baseA[jj] = xb + (size_t)t * D_DIM + cg * 8;
  }
  {
    const short* wB = ((wid & 2) ? wu : wg) + (size_t)e * H_DIM * D_DIM;
    int rb = (wid & 1) * 32;
    ldsB = ((wid & 2) ? Bus : Bgs) + rb * 64;
#pragma unroll
    for (int jj = 0; jj < 4; ++jj) {
      int h = h0 + rb + jj * 8 + (lane >> 3);
      baseB[jj] = wB + (size_t)h * D_DIM + cg * 8;
    }
  }

  int ml = lane & 15, quad = lane >> 4;
  int m0w = wid * 64;
  f32x4 accG[4][4], accU[4][4];
#pragma unroll
  for (int mf = 0; mf < 4; ++mf)
#pragma unroll
    for (int nf = 0; nf < 4; ++nf) {
      accG[mf][nf] = (f32x4){0, 0, 0, 0};
      accU[mf][nf] = (f32x4){0, 0, 0, 0};
    }

  for (int kt = 0; kt < D_DIM / 64; ++kt) {
    int kb = kt * 64;
#pragma unroll
    for (int jj = 0; jj < 8; ++jj)
      llds16(baseA[jj] + kb, ldsA + jj * 8 * 64);
#pragma unroll
    for (int jj = 0; jj < 4; ++jj)
      llds16(baseB[jj] + kb, ldsB + jj * 8 * 64);
    __syncthreads();
#pragma unroll
    for (int ks = 0; ks < 2; ++ks) {
      int cs = ((quad + ks * 4) ^ (ml & 7)) * 8;
      short8 a[4], bg[4], bu[4];
#pragma unroll
      for (int mf = 0; mf < 4; ++mf)
        a[mf] = *(const short8*)&As[(m0w + mf * 16 + ml) * 64 + cs];
#pragma unroll
      for (int nf = 0; nf < 4; ++nf) {
        bg[nf] = *(const short8*)&Bgs[(nf * 16 + ml) * 64 + cs];
        bu[nf] = *(const short8*)&Bus[(nf * 16 + ml) * 64 + cs];
      }
#pragma unroll
      for (int mf = 0; mf < 4; ++mf)
#pragma unroll
        for (int nf = 0; nf < 4; ++nf) {
          accG[mf][nf] = __builtin_amdgcn_mfma_f32_16x16x32_bf16(a[mf], bg[nf], accG[mf][nf], 0, 0, 0);
          accU[mf][nf] = __builtin_amdgcn_mfma_f32_16x16x32_bf16(a[mf], bu[nf], accU[mf][nf], 0, 0, 0);
        }
    }
    __syncthreads();
  }

#pragma unroll
  for (int mf = 0; mf < 4; ++mf)
#pragma unroll
    for (int r = 0; r < 4; ++r) {
      int rl = m0w + mf * 16 + quad * 4 + r;
      int arow = s_row[rl];
      if (arow >= 0) {
        float pr = s_pr[rl];
#pragma unroll
        for (int nf = 0; nf < 4; ++nf) {
          float g = accG[mf][nf][r], u = accU[mf][nf][r];
          float val = pr * (g / (1.f + __expf(-g))) * u;
          act[(size_t)arow * H_DIM + h0 + nf * 16 + ml] = f2bs(val);
        }
      }
    }
}

// ---------- down GEMM: partial[ksb][t][d] = act-slice @ wd (plain stores) ----------
// 128x128 tile, Ksplit=4 across blockIdx.z
__global__ void __launch_bounds__(256, 3) down_kernel(
    const short* __restrict__ act, const short* __restrict__ wd,
    float* __restrict__ partial) {
  __shared__ __align__(16) short As[128 * 64];  // 16 KB
  __shared__ __align__(16) short Bs[128 * 64];  // 16 KB
  int d0 = blockIdx.x * 128;
  int t0 = blockIdx.y * 128;
  int ksb = blockIdx.z;  // kt range [ksb*16, ksb*16+16)
  int tid = threadIdx.x, lane = tid & 63, wid = tid >> 6;
  int cg = (lane & 7) ^ (lane >> 3);

  const short* baseA[4];
  const short* baseB[4];
  short* ldsA = As + (size_t)wid * 32 * 64;
  short* ldsB = Bs + (size_t)wid * 32 * 64;
#pragma unroll
  for (int jj = 0; jj < 4; ++jj) {
    int r = wid * 32 + jj * 8 + (lane >> 3);
    baseA[jj] = act + (size_t)(2 * (t0 + r)) * H_DIM + cg * 8;
    int d = d0 + wid * 32 + jj * 8 + (lane >> 3);
    baseB[jj] = wd + (size_t)d * H_DIM + cg * 8;
  }

  int ml = lane & 15, quad = lane >> 4;
  int m0w = (wid & 1) * 64, n0w = (wid >> 1) * 64;
  f32x4 acc[4][4];
#pragma unroll
  for (int mf = 0; mf < 4; ++mf)
#pragma unroll
    for (int nf = 0; nf < 4; ++nf) acc[mf][nf] = (f32x4){0, 0, 0, 0};

  for (int kt = ksb * 16; kt < ksb * 16 + 16; ++kt) {
    size_t offA = (size_t)(kt & 1) * H_DIM + (kt >> 1) * 64;
    int offB = (kt >> 1) * 64;
#pragma unroll
    for (int jj = 0; jj < 4; ++jj) {
      llds16(baseA[jj] + offA, ldsA + jj * 8 * 64);
      llds16(baseB[jj] + offB, ldsB + jj * 8 * 64);
    }
    __syncthreads();
#pragma unroll
    for (int ks = 0; ks < 2; ++ks) {
      int cs = ((quad + ks * 4) ^ (ml & 7)) * 8;
      short8 a[4], b[4];
#pragma unroll
      for (int mf = 0; mf < 4; ++mf)
        a[mf] = *(const short8*)&As[(m0w + mf * 16 + ml) * 64 + cs];
#pragma unroll
      for (int nf = 0; nf < 4; ++nf)
        b[nf] = *(const short8*)&Bs[(n0w + nf * 16 + ml) * 64 + cs];
#pragma unroll
      for (int mf = 0; mf < 4; ++mf)
#pragma unroll
        for (int nf = 0; nf < 4; ++nf)
          acc[mf][nf] = __builtin_amdgcn_mfma_f32_16x16x32_bf16(a[mf], b[nf], acc[mf][nf], 0, 0, 0);
    }
    __syncthreads();
  }

  float* pout = partial + (size_t)ksb * N_TOK * D_DIM;
#pragma unroll
  for (int mf = 0; mf < 4; ++mf)
#pragma unroll
    for (int r = 0; r < 4; ++r) {
      int t = t0 + m0w + mf * 16 + quad * 4 + r;
#pragma unroll
      for (int nf = 0; nf < 4; ++nf)
        pout[(size_t)t * D_DIM + d0 + n0w + nf * 16 + ml] = acc[mf][nf][r];
    }
}

// ---------- split-K reduce: out = sum of 4 partials ----------
__global__ void __launch_bounds__(256) reduce_kernel(
    const float* __restrict__ partial, float* __restrict__ out) {
  int i = blockIdx.x * 256 + threadIdx.x;  // float4 index
  const int Q = N_TOK * D_DIM / 4;
  const float4* p = (const float4*)partial;
  float4 a = p[i], b = p[i + Q], c = p[i + 2 * Q], d = p[i + 3 * Q];
  float4 r = {a.x + b.x + c.x + d.x, a.y + b.y + c.y + d.y,
              a.z + b.z + c.z + d.z, a.w + b.w + c.w + d.w};
  ((float4*)out)[i] = r;
}

extern "C" void kernel_launch(void* const* d_in, const int* in_sizes, int n_in,
                              void* d_out, int out_size, void* d_ws, size_t ws_size,
                              hipStream_t stream) {
  const float* x = (const float*)d_in[0];
  const float* wr = (const float*)d_in[1];
  const float* wg = (const float*)d_in[2];
  const float* wu = (const float*)d_in[3];
  const float* wd = (const float*)d_in[4];
  float* out = (float*)d_out;

  char* ws = (char*)d_ws;
  size_t off = 0;
  auto alloc = [&](size_t bytes) {
    char* p = ws + off;
    off += (bytes + 255) & ~(size_t)255;
    return p;
  };
  short* xb = (short*)alloc((size_t)N_TOK * D_DIM * 2);
  short* wgb = (short*)alloc((size_t)E_NUM * H_DIM * D_DIM * 2);  // [e*H+h][d]
  short* wub = (short*)alloc((size_t)E_NUM * H_DIM * D_DIM * 2);
  short* wdb = (short*)alloc((size_t)D_DIM * H_DIM * 2);          // [d][h]
  short* act = (short*)alloc((size_t)N_TOK * 2 * H_DIM * 2);      // [2t+slot][H]
  float* partial = (float*)alloc((size_t)4 * N_TOK * D_DIM * 4);  // split-K partials
  int* cnt_blk = (int*)alloc((size_t)RB_NUM * E_NUM * 4);
  int* tok_bkt = (int*)alloc((size_t)E_NUM * RB_NUM * 16 * 4);
  float* p_bkt = (float*)alloc((size_t)E_NUM * RB_NUM * 16 * 4);
  float* psum_blk = (float*)alloc((size_t)RB_NUM * E_NUM * 4);

  prep_router_kernel<<<RB_NUM + 17408, 256, 0, stream>>>(
      wg, wu, wd, x, wr, wgb, wub, wdb, xb, cnt_blk, tok_bkt, p_bkt, psum_blk);
  moe_gateup_kernel<<<dim3(H_DIM / 64, N_TOK / 256, E_NUM + 1), 256, 0, stream>>>(
      xb, wgb, wub, cnt_blk, tok_bkt, p_bkt, psum_blk, act,
      out + (size_t)N_TOK * D_DIM);
  down_kernel<<<dim3(D_DIM / 128, N_TOK / 128, 4), 256, 0, stream>>>(act, wdb, partial);
  reduce_kernel<<<N_TOK * D_DIM / 4 / 256, 256, 0, stream>>>(partial, out);
}